// Round 1
// baseline (2824.525 us; speedup 1.0000x reference)
//
#include <hip/hip_runtime.h>

#define D 128
constexpr int NW = 30000;
constexpr int NT = 2000;
constexpr int NDOC = 20000;

// ---------------------------------------------------------------------------
// Edge aggregation: S[dst] += w * X[src]  (128 floats), deg[dst] += 1,
// wsum[dst] += w (optional). 32 threads per edge, 4 floats per thread.
// ---------------------------------------------------------------------------
__global__ __launch_bounds__(256) void agg_kernel(
    const float* __restrict__ X, const int* __restrict__ src,
    const int* __restrict__ dst, const float* __restrict__ w, int E,
    float* __restrict__ S, float* __restrict__ deg, float* __restrict__ wsum)
{
    long long t = (long long)blockIdx.x * blockDim.x + threadIdx.x;
    int e = (int)(t >> 5);
    int lane = (int)(t & 31);
    if (e >= E) return;
    int s = src[e];
    int d = dst[e];
    float we = w[e];
    float4 v = ((const float4*)(X + (long long)s * D))[lane];
    float* o = S + (long long)d * D + lane * 4;
    atomicAdd(o + 0, v.x * we);
    atomicAdd(o + 1, v.y * we);
    atomicAdd(o + 2, v.z * we);
    atomicAdd(o + 3, v.w * we);
    if (lane == 0) {
        atomicAdd(deg + d, 1.0f);
        if (wsum) atomicAdd(wsum + d, we);
    }
}

// ---------------------------------------------------------------------------
// Y = X @ W  [n x 128] x [128 x 128], optionally normalized:
//   if deg != null:  Y[i] = (deg[i]>0 ? (X[i]@W + wsum[i]*bias)/deg[i] : 0)
//                           + (T ? (degT[i]>0 ? T[i]/degT[i] : 0) : 0)
// Block: 256 threads = 32 col-groups (4 cols each) x 8 row-groups.
// 32 rows per block. W staged in LDS (64KB), X rows staged in LDS (16KB).
// ---------------------------------------------------------------------------
__global__ __launch_bounds__(256) void mm_kernel(
    const float* __restrict__ X, const float* __restrict__ W,
    const float* __restrict__ deg, const float* __restrict__ wsum,
    const float* __restrict__ bias,
    const float* __restrict__ T, const float* __restrict__ degT,
    float* __restrict__ Y, int n)
{
    __shared__ float Wl[D * D];
    __shared__ float xs[32][D];
    int tid = threadIdx.x;

    for (int i = tid; i < D * D / 4; i += 256)
        ((float4*)Wl)[i] = ((const float4*)W)[i];

    int row0 = blockIdx.x * 32;
    for (int i = tid; i < 32 * (D / 4); i += 256) {
        int r = i / (D / 4);
        int c4 = i % (D / 4);
        float4 v = make_float4(0.f, 0.f, 0.f, 0.f);
        if (row0 + r < n)
            v = ((const float4*)(X + (long long)(row0 + r) * D))[c4];
        ((float4*)&xs[r][0])[c4] = v;
    }
    __syncthreads();

    int cg = tid & 31;   // column group: cols cg*4 .. cg*4+3
    int rg = tid >> 5;   // row group: rows rg, rg+8, rg+16, rg+24
    int col0 = cg * 4;

    float acc[4][4];
#pragma unroll
    for (int j = 0; j < 4; ++j)
#pragma unroll
        for (int c = 0; c < 4; ++c) acc[j][c] = 0.f;

#pragma unroll 4
    for (int k = 0; k < D; ++k) {
        float4 wv = *(const float4*)&Wl[k * D + col0];
#pragma unroll
        for (int j = 0; j < 4; ++j) {
            float xv = xs[rg + j * 8][k];
            acc[j][0] = fmaf(xv, wv.x, acc[j][0]);
            acc[j][1] = fmaf(xv, wv.y, acc[j][1]);
            acc[j][2] = fmaf(xv, wv.z, acc[j][2]);
            acc[j][3] = fmaf(xv, wv.w, acc[j][3]);
        }
    }

#pragma unroll
    for (int j = 0; j < 4; ++j) {
        int row = row0 + rg + j * 8;
        if (row >= n) continue;
        float4 y;
        float* yp = &y.x;
        if (deg) {
            float dg = deg[row];
            float ws = wsum ? wsum[row] : 0.f;
#pragma unroll
            for (int c = 0; c < 4; ++c)
                yp[c] = dg > 0.f ? (acc[j][c] + ws * bias[col0 + c]) / dg : 0.f;
            if (T) {
                float dt = degT[row];
                if (dt > 0.f) {
                    float4 tv = *(const float4*)&T[(long long)row * D + col0];
                    y.x += tv.x / dt;
                    y.y += tv.y / dt;
                    y.z += tv.z / dt;
                    y.w += tv.w / dt;
                }
            }
        } else {
#pragma unroll
            for (int c = 0; c < 4; ++c) yp[c] = acc[j][c];
        }
        *(float4*)&Y[(long long)row * D + col0] = y;
    }
}

// ---------------------------------------------------------------------------
// Wh_td = P_td + b_td + causal*Pc - rm_td*Pn ; same for tt.
// causal = (effect != 0); rm_* = bern_* * (effect == 0).
// ---------------------------------------------------------------------------
__global__ __launch_bounds__(256) void combine_topic_kernel(
    const float* __restrict__ P_td, const float* __restrict__ P_tt,
    const float* __restrict__ Pc, const float* __restrict__ Pn,
    const float* __restrict__ effect, const float* __restrict__ bern_td,
    const float* __restrict__ bern_tt,
    const float* __restrict__ b_td, const float* __restrict__ b_tt,
    float* __restrict__ Wh_td, float* __restrict__ Wh_tt)
{
    int i = blockIdx.x * 256 + threadIdx.x;
    if (i >= NT * D) return;
    int row = i >> 7;
    int col = i & (D - 1);
    float eff = effect[row];
    float causal = (eff != 0.f) ? 1.f : 0.f;
    float zero = (eff == 0.f) ? 1.f : 0.f;
    float rmtd = bern_td[row] * zero;
    float rmtt = bern_tt[row] * zero;
    float pc = Pc[i];
    float pn = Pn[i];
    Wh_td[i] = P_td[i] + b_td[col] + causal * pc - rmtd * pn;
    Wh_tt[i] = P_tt[i] + b_tt[col] + causal * pc - rmtt * pn;
}

extern "C" void kernel_launch(void* const* d_in, const int* in_sizes, int n_in,
                              void* d_out, int out_size, void* d_ws, size_t ws_size,
                              hipStream_t stream)
{
    const float* feat_word  = (const float*)d_in[0];
    const float* feat_topic = (const float*)d_in[1];
    const float* effect     = (const float*)d_in[2];
    const float* bern_td    = (const float*)d_in[3];
    const float* bern_tt    = (const float*)d_in[4];
    const int*   src_ww = (const int*)d_in[5];
    const int*   dst_ww = (const int*)d_in[6];
    const float* w_ww   = (const float*)d_in[7];
    const int*   src_wt = (const int*)d_in[8];
    const int*   dst_wt = (const int*)d_in[9];
    const float* w_wt   = (const float*)d_in[10];
    const int*   src_wd = (const int*)d_in[11];
    const int*   dst_wd = (const int*)d_in[12];
    const float* w_wd   = (const float*)d_in[13];
    const int*   src_td = (const int*)d_in[14];
    const int*   dst_td = (const int*)d_in[15];
    const float* w_td   = (const float*)d_in[16];
    const int*   src_tt = (const int*)d_in[17];
    const int*   dst_tt = (const int*)d_in[18];
    const float* w_tt   = (const float*)d_in[19];
    const float* W_ww = (const float*)d_in[20];
    const float* b_ww = (const float*)d_in[21];
    const float* W_wt = (const float*)d_in[22];
    const float* b_wt = (const float*)d_in[23];
    const float* W_wd = (const float*)d_in[24];
    const float* b_wd = (const float*)d_in[25];
    const float* W_td = (const float*)d_in[26];
    const float* b_td = (const float*)d_in[27];
    const float* W_tt = (const float*)d_in[28];
    const float* b_tt = (const float*)d_in[29];
    const float* W_causal = (const float*)d_in[30];
    const float* W_noise  = (const float*)d_in[31];

    const int E_ww = in_sizes[5];
    const int E_wt = in_sizes[8];
    const int E_wd = in_sizes[11];
    const int E_td = in_sizes[14];
    const int E_tt = in_sizes[17];

    // ---- workspace layout (floats) ----
    float* ws = (float*)d_ws;
    float* S_word  = ws; ws += (long long)NW * D;
    float* deg_word= ws; ws += NW;
    float* wsum_ww = ws; ws += NW;
    float* S_wt    = ws; ws += (long long)NT * D;
    float* deg_wt  = ws; ws += NT;
    float* wsum_wt = ws; ws += NT;
    float* T_tt    = ws; ws += (long long)NT * D;
    float* deg_tt  = ws; ws += NT;
    float* S_wd    = ws; ws += (long long)NDOC * D;
    float* deg_wd  = ws; ws += NDOC;
    float* wsum_wd = ws; ws += NDOC;
    float* T_td    = ws; ws += (long long)NDOC * D;
    float* deg_td  = ws; ws += NDOC;
    size_t zero_floats = (size_t)(ws - (float*)d_ws);
    float* P_td  = ws; ws += (long long)NT * D;
    float* P_tt  = ws; ws += (long long)NT * D;
    float* Pc    = ws; ws += (long long)NT * D;
    float* Pn    = ws; ws += (long long)NT * D;
    float* Wh_td = ws; ws += (long long)NT * D;
    float* Wh_tt = ws; ws += (long long)NT * D;

    hipMemsetAsync(d_ws, 0, zero_floats * sizeof(float), stream);

    float* h_word  = (float*)d_out;
    float* h_topic = h_word + (long long)NW * D;
    float* h_doc   = h_topic + (long long)NT * D;

    auto agg_blocks = [](int E) {
        return (unsigned)(((long long)E * 32 + 255) / 256);
    };

    // Phase 1: ww aggregation on raw word features, then projection.
    agg_kernel<<<agg_blocks(E_ww), 256, 0, stream>>>(
        feat_word, src_ww, dst_ww, w_ww, E_ww, S_word, deg_word, wsum_ww);
    mm_kernel<<<(NW + 31) / 32, 256, 0, stream>>>(
        S_word, W_ww, deg_word, wsum_ww, b_ww, nullptr, nullptr, h_word, NW);

    // Topic-side Wh precompute (small: 4 matmuls of 2000 rows + combine).
    mm_kernel<<<(NT + 31) / 32, 256, 0, stream>>>(
        feat_topic, W_td, nullptr, nullptr, nullptr, nullptr, nullptr, P_td, NT);
    mm_kernel<<<(NT + 31) / 32, 256, 0, stream>>>(
        feat_topic, W_tt, nullptr, nullptr, nullptr, nullptr, nullptr, P_tt, NT);
    mm_kernel<<<(NT + 31) / 32, 256, 0, stream>>>(
        feat_topic, W_causal, nullptr, nullptr, nullptr, nullptr, nullptr, Pc, NT);
    mm_kernel<<<(NT + 31) / 32, 256, 0, stream>>>(
        feat_topic, W_noise, nullptr, nullptr, nullptr, nullptr, nullptr, Pn, NT);
    combine_topic_kernel<<<(NT * D + 255) / 256, 256, 0, stream>>>(
        P_td, P_tt, Pc, Pn, effect, bern_td, bern_tt, b_td, b_tt, Wh_td, Wh_tt);

    // Phase 2 aggregations (wt/wd gather h_word; td/tt gather Wh_* directly).
    agg_kernel<<<agg_blocks(E_wt), 256, 0, stream>>>(
        h_word, src_wt, dst_wt, w_wt, E_wt, S_wt, deg_wt, wsum_wt);
    agg_kernel<<<agg_blocks(E_tt), 256, 0, stream>>>(
        Wh_tt, src_tt, dst_tt, w_tt, E_tt, T_tt, deg_tt, nullptr);
    agg_kernel<<<agg_blocks(E_wd), 256, 0, stream>>>(
        h_word, src_wd, dst_wd, w_wd, E_wd, S_wd, deg_wd, wsum_wd);
    agg_kernel<<<agg_blocks(E_td), 256, 0, stream>>>(
        Wh_td, src_td, dst_td, w_td, E_td, T_td, deg_td, nullptr);

    // Final projections + cross-relation sums.
    mm_kernel<<<(NT + 31) / 32, 256, 0, stream>>>(
        S_wt, W_wt, deg_wt, wsum_wt, b_wt, T_tt, deg_tt, h_topic, NT);
    mm_kernel<<<(NDOC + 31) / 32, 256, 0, stream>>>(
        S_wd, W_wd, deg_wd, wsum_wd, b_wd, T_td, deg_td, h_doc, NDOC);

    (void)n_in; (void)in_sizes; (void)out_size; (void)ws_size;
}

// Round 3
// 627.163 us; speedup vs baseline: 4.5037x; 4.5037x over previous
//
#include <hip/hip_runtime.h>

#define D 128
constexpr int NW = 30000;
constexpr int NT = 2000;
constexpr int NDOC = 20000;
constexpr int NSLOT = NW + NT + NT + NDOC + NDOC;   // 74000 destination slots
constexpr int SEG_WW = 0;
constexpr int SEG_WT = NW;                // 30000
constexpr int SEG_TT = NW + NT;           // 32000
constexpr int SEG_WD = NW + 2 * NT;       // 34000
constexpr int SEG_TD = NW + 2 * NT + NDOC; // 54000

// ---------------------------------------------------------------------------
// CSR build: count -> scan -> scatter. Only int atomics (1.44M total).
// ---------------------------------------------------------------------------
__global__ __launch_bounds__(256) void count_kernel(
    const int* __restrict__ dst, int E, int seg, int* __restrict__ counts)
{
    int e = blockIdx.x * 256 + threadIdx.x;
    if (e < E) atomicAdd(&counts[seg + dst[e]], 1);
}

// phase 1: per-block exclusive scan of counts into offsets, block totals out.
__global__ __launch_bounds__(256) void scan1_kernel(
    const int* __restrict__ counts, int n, int n1,
    int* __restrict__ offsets, int* __restrict__ blocksums)
{
    __shared__ int tmp[256];
    int tid = threadIdx.x;
    int i = blockIdx.x * 256 + tid;
    int v = (i < n) ? counts[i] : 0;
    tmp[tid] = v;
    __syncthreads();
    for (int off = 1; off < 256; off <<= 1) {
        int t = (tid >= off) ? tmp[tid - off] : 0;
        __syncthreads();
        tmp[tid] += t;
        __syncthreads();
    }
    if (i < n1) offsets[i] = tmp[tid] - v;   // exclusive
    if (tid == 255) blocksums[blockIdx.x] = tmp[255];
}

// phase 2: add carry (sum of preceding block totals), duplicate into cursor.
__global__ __launch_bounds__(256) void scan3_kernel(
    int* __restrict__ offsets, int* __restrict__ cursor,
    const int* __restrict__ blocksums, int n1)
{
    __shared__ int red[256];
    int tid = threadIdx.x;
    int acc = 0;
    for (int i = tid; i < blockIdx.x; i += 256) acc += blocksums[i];
    red[tid] = acc;
    __syncthreads();
    for (int off = 128; off > 0; off >>= 1) {
        if (tid < off) red[tid] += red[tid + off];
        __syncthreads();
    }
    int carry = red[0];
    int i = blockIdx.x * 256 + tid;
    if (i < n1) {
        int v = offsets[i] + carry;
        offsets[i] = v;
        cursor[i] = v;
    }
}

__global__ __launch_bounds__(256) void scatter_kernel(
    const int* __restrict__ src, const int* __restrict__ dst,
    const float* __restrict__ w, int E, int seg,
    int* __restrict__ cursor, int* __restrict__ ssrc, float* __restrict__ sw)
{
    int e = blockIdx.x * 256 + threadIdx.x;
    if (e >= E) return;
    int p = atomicAdd(&cursor[seg + dst[e]], 1);
    ssrc[p] = src[e];
    sw[p] = w[e];
}

// ---------------------------------------------------------------------------
// Segmented reduction: one wave (64 lanes) per dst slot, float2 per lane.
// S[slot] = sum_e w_e * X[src_e]; degf[slot] = #edges; wsumf[slot] = sum w.
// No atomics: each output row written exactly once.
// ---------------------------------------------------------------------------
__global__ __launch_bounds__(256) void reduce_kernel(
    const float* __restrict__ X, const int* __restrict__ offsets,
    const int* __restrict__ ssrc, const float* __restrict__ sw,
    int slot0, int nslots, float* __restrict__ S,
    float* __restrict__ degf, float* __restrict__ wsumf)
{
    int wave = threadIdx.x >> 6;
    int lane = threadIdx.x & 63;
    int rel = blockIdx.x * 4 + wave;
    if (rel >= nslots) return;
    int slot = slot0 + rel;
    int start = offsets[slot], end = offsets[slot + 1];
    float ax = 0.f, ay = 0.f, wsl = 0.f;
    int j = start;
    for (; j + 1 < end; j += 2) {
        int s0 = ssrc[j], s1 = ssrc[j + 1];
        float w0 = sw[j], w1 = sw[j + 1];
        float2 v0 = *(const float2*)(X + (long long)s0 * D + lane * 2);
        float2 v1 = *(const float2*)(X + (long long)s1 * D + lane * 2);
        ax = fmaf(w0, v0.x, ax); ay = fmaf(w0, v0.y, ay);
        ax = fmaf(w1, v1.x, ax); ay = fmaf(w1, v1.y, ay);
        wsl += w0 + w1;
    }
    if (j < end) {
        int s0 = ssrc[j];
        float w0 = sw[j];
        float2 v0 = *(const float2*)(X + (long long)s0 * D + lane * 2);
        ax = fmaf(w0, v0.x, ax); ay = fmaf(w0, v0.y, ay);
        wsl += w0;
    }
    *(float2*)(S + (long long)slot * D + lane * 2) = make_float2(ax, ay);
    if (lane == 0) {
        degf[slot] = (float)(end - start);
        if (wsumf) wsumf[slot] = wsl;
    }
}

// ---------------------------------------------------------------------------
// Y = X @ W  [n x 128] x [128 x 128], optionally normalized:
//   if deg != null:  Y[i] = (deg[i]>0 ? (X[i]@W + wsum[i]*bias)/deg[i] : 0)
//                           + (T ? (degT[i]>0 ? T[i]/degT[i] : 0) : 0)
// ---------------------------------------------------------------------------
__global__ __launch_bounds__(256) void mm_kernel(
    const float* __restrict__ X, const float* __restrict__ W,
    const float* __restrict__ deg, const float* __restrict__ wsum,
    const float* __restrict__ bias,
    const float* __restrict__ T, const float* __restrict__ degT,
    float* __restrict__ Y, int n)
{
    __shared__ float Wl[D * D];
    __shared__ float xs[32][D];
    int tid = threadIdx.x;

    for (int i = tid; i < D * D / 4; i += 256)
        ((float4*)Wl)[i] = ((const float4*)W)[i];

    int row0 = blockIdx.x * 32;
    for (int i = tid; i < 32 * (D / 4); i += 256) {
        int r = i / (D / 4);
        int c4 = i % (D / 4);
        float4 v = make_float4(0.f, 0.f, 0.f, 0.f);
        if (row0 + r < n)
            v = ((const float4*)(X + (long long)(row0 + r) * D))[c4];
        ((float4*)&xs[r][0])[c4] = v;
    }
    __syncthreads();

    int cg = tid & 31;
    int rg = tid >> 5;
    int col0 = cg * 4;

    float acc[4][4];
#pragma unroll
    for (int j = 0; j < 4; ++j)
#pragma unroll
        for (int c = 0; c < 4; ++c) acc[j][c] = 0.f;

#pragma unroll 4
    for (int k = 0; k < D; ++k) {
        float4 wv = *(const float4*)&Wl[k * D + col0];
#pragma unroll
        for (int j = 0; j < 4; ++j) {
            float xv = xs[rg + j * 8][k];
            acc[j][0] = fmaf(xv, wv.x, acc[j][0]);
            acc[j][1] = fmaf(xv, wv.y, acc[j][1]);
            acc[j][2] = fmaf(xv, wv.z, acc[j][2]);
            acc[j][3] = fmaf(xv, wv.w, acc[j][3]);
        }
    }

#pragma unroll
    for (int j = 0; j < 4; ++j) {
        int row = row0 + rg + j * 8;
        if (row >= n) continue;
        float4 y;
        float* yp = &y.x;
        if (deg) {
            float dg = deg[row];
            float ws = wsum ? wsum[row] : 0.f;
#pragma unroll
            for (int c = 0; c < 4; ++c)
                yp[c] = dg > 0.f ? (acc[j][c] + ws * bias[col0 + c]) / dg : 0.f;
            if (T) {
                float dt = degT[row];
                if (dt > 0.f) {
                    float4 tv = *(const float4*)&T[(long long)row * D + col0];
                    y.x += tv.x / dt;
                    y.y += tv.y / dt;
                    y.z += tv.z / dt;
                    y.w += tv.w / dt;
                }
            }
        } else {
#pragma unroll
            for (int c = 0; c < 4; ++c) yp[c] = acc[j][c];
        }
        *(float4*)&Y[(long long)row * D + col0] = y;
    }
}

// ---------------------------------------------------------------------------
// Wh_td = P_td + b_td + causal*Pc - rm_td*Pn ; same for tt.
// ---------------------------------------------------------------------------
__global__ __launch_bounds__(256) void combine_topic_kernel(
    const float* __restrict__ P_td, const float* __restrict__ P_tt,
    const float* __restrict__ Pc, const float* __restrict__ Pn,
    const float* __restrict__ effect, const float* __restrict__ bern_td,
    const float* __restrict__ bern_tt,
    const float* __restrict__ b_td, const float* __restrict__ b_tt,
    float* __restrict__ Wh_td, float* __restrict__ Wh_tt)
{
    int i = blockIdx.x * 256 + threadIdx.x;
    if (i >= NT * D) return;
    int row = i >> 7;
    int col = i & (D - 1);
    float eff = effect[row];
    float causal = (eff != 0.f) ? 1.f : 0.f;
    float zero = (eff == 0.f) ? 1.f : 0.f;
    float rmtd = bern_td[row] * zero;
    float rmtt = bern_tt[row] * zero;
    float pc = Pc[i];
    float pn = Pn[i];
    Wh_td[i] = P_td[i] + b_td[col] + causal * pc - rmtd * pn;
    Wh_tt[i] = P_tt[i] + b_tt[col] + causal * pc - rmtt * pn;
}

extern "C" void kernel_launch(void* const* d_in, const int* in_sizes, int n_in,
                              void* d_out, int out_size, void* d_ws, size_t ws_size,
                              hipStream_t stream)
{
    const float* feat_word  = (const float*)d_in[0];
    const float* feat_topic = (const float*)d_in[1];
    const float* effect     = (const float*)d_in[2];
    const float* bern_td    = (const float*)d_in[3];
    const float* bern_tt    = (const float*)d_in[4];
    const int*   src_ww = (const int*)d_in[5];
    const int*   dst_ww = (const int*)d_in[6];
    const float* w_ww   = (const float*)d_in[7];
    const int*   src_wt = (const int*)d_in[8];
    const int*   dst_wt = (const int*)d_in[9];
    const float* w_wt   = (const float*)d_in[10];
    const int*   src_wd = (const int*)d_in[11];
    const int*   dst_wd = (const int*)d_in[12];
    const float* w_wd   = (const float*)d_in[13];
    const int*   src_td = (const int*)d_in[14];
    const int*   dst_td = (const int*)d_in[15];
    const float* w_td   = (const float*)d_in[16];
    const int*   src_tt = (const int*)d_in[17];
    const int*   dst_tt = (const int*)d_in[18];
    const float* w_tt   = (const float*)d_in[19];
    const float* W_ww = (const float*)d_in[20];
    const float* b_ww = (const float*)d_in[21];
    const float* W_wt = (const float*)d_in[22];
    const float* b_wt = (const float*)d_in[23];
    const float* W_wd = (const float*)d_in[24];
    const float* b_wd = (const float*)d_in[25];
    const float* W_td = (const float*)d_in[26];
    const float* b_td = (const float*)d_in[27];
    const float* W_tt = (const float*)d_in[28];
    const float* b_tt = (const float*)d_in[29];
    const float* W_causal = (const float*)d_in[30];
    const float* W_noise  = (const float*)d_in[31];

    const int E_ww = in_sizes[5];
    const int E_wt = in_sizes[8];
    const int E_wd = in_sizes[11];
    const int E_td = in_sizes[14];
    const int E_tt = in_sizes[17];
    const int E_total = E_ww + E_wt + E_wd + E_td + E_tt;

    // ---- workspace layout (4-byte units) ----
    float* ws = (float*)d_ws;
    float* S      = ws; ws += (long long)NSLOT * D;    // aggregated sums per slot
    float* degf   = ws; ws += NSLOT;
    float* wsumf  = ws; ws += NSLOT;
    int*   counts   = (int*)ws; ws += NSLOT;
    int*   offsets  = (int*)ws; ws += NSLOT + 1;
    int*   cursor   = (int*)ws; ws += NSLOT + 1;
    int*   blocksums= (int*)ws; ws += 512;
    int*   ssrc     = (int*)ws; ws += E_total;
    float* sw       = ws;       ws += E_total;
    float* Wh_td    = ws;       ws += (long long)NT * D;
    float* Wh_tt    = ws;       ws += (long long)NT * D;
    // P_* buffers overlay the doc-segment region of S: that region is only
    // written by the wd/td reduces, which launch AFTER combine consumes P_*.
    float* Pbase = S + (long long)SEG_WD * D;
    float* P_td = Pbase;
    float* P_tt = Pbase + (long long)NT * D;
    float* Pc   = Pbase + (long long)2 * NT * D;
    float* Pn   = Pbase + (long long)3 * NT * D;

    hipMemsetAsync(counts, 0, NSLOT * sizeof(int), stream);

    float* h_word  = (float*)d_out;
    float* h_topic = h_word + (long long)NW * D;
    float* h_doc   = h_topic + (long long)NT * D;

    auto nb = [](int n) { return (unsigned)((n + 255) / 256); };

    // ---- CSR build over the combined 74000-slot dst space ----
    count_kernel<<<nb(E_ww), 256, 0, stream>>>(dst_ww, E_ww, SEG_WW, counts);
    count_kernel<<<nb(E_wt), 256, 0, stream>>>(dst_wt, E_wt, SEG_WT, counts);
    count_kernel<<<nb(E_tt), 256, 0, stream>>>(dst_tt, E_tt, SEG_TT, counts);
    count_kernel<<<nb(E_wd), 256, 0, stream>>>(dst_wd, E_wd, SEG_WD, counts);
    count_kernel<<<nb(E_td), 256, 0, stream>>>(dst_td, E_td, SEG_TD, counts);

    int n1 = NSLOT + 1;
    unsigned scan_blocks = nb(n1);
    scan1_kernel<<<scan_blocks, 256, 0, stream>>>(counts, NSLOT, n1, offsets, blocksums);
    scan3_kernel<<<scan_blocks, 256, 0, stream>>>(offsets, cursor, blocksums, n1);

    scatter_kernel<<<nb(E_ww), 256, 0, stream>>>(src_ww, dst_ww, w_ww, E_ww, SEG_WW, cursor, ssrc, sw);
    scatter_kernel<<<nb(E_wt), 256, 0, stream>>>(src_wt, dst_wt, w_wt, E_wt, SEG_WT, cursor, ssrc, sw);
    scatter_kernel<<<nb(E_tt), 256, 0, stream>>>(src_tt, dst_tt, w_tt, E_tt, SEG_TT, cursor, ssrc, sw);
    scatter_kernel<<<nb(E_wd), 256, 0, stream>>>(src_wd, dst_wd, w_wd, E_wd, SEG_WD, cursor, ssrc, sw);
    scatter_kernel<<<nb(E_td), 256, 0, stream>>>(src_td, dst_td, w_td, E_td, SEG_TD, cursor, ssrc, sw);

    // ---- Phase 1: ww aggregation on raw word features, then projection ----
    reduce_kernel<<<(NW + 3) / 4, 256, 0, stream>>>(   // FIXED: was 118 blocks, need 7500
        feat_word, offsets, ssrc, sw, SEG_WW, NW, S, degf, wsumf);
    mm_kernel<<<(NW + 31) / 32, 256, 0, stream>>>(
        S + (long long)SEG_WW * D, W_ww, degf + SEG_WW, wsumf + SEG_WW, b_ww,
        nullptr, nullptr, h_word, NW);

    // ---- Topic-side Wh precompute ----
    mm_kernel<<<(NT + 31) / 32, 256, 0, stream>>>(
        feat_topic, W_td, nullptr, nullptr, nullptr, nullptr, nullptr, P_td, NT);
    mm_kernel<<<(NT + 31) / 32, 256, 0, stream>>>(
        feat_topic, W_tt, nullptr, nullptr, nullptr, nullptr, nullptr, P_tt, NT);
    mm_kernel<<<(NT + 31) / 32, 256, 0, stream>>>(
        feat_topic, W_causal, nullptr, nullptr, nullptr, nullptr, nullptr, Pc, NT);
    mm_kernel<<<(NT + 31) / 32, 256, 0, stream>>>(
        feat_topic, W_noise, nullptr, nullptr, nullptr, nullptr, nullptr, Pn, NT);
    combine_topic_kernel<<<nb(NT * D), 256, 0, stream>>>(
        P_td, P_tt, Pc, Pn, effect, bern_td, bern_tt, b_td, b_tt, Wh_td, Wh_tt);

    // ---- Phase 2 reduces (wt/wd gather h_word; tt/td gather Wh_*) ----
    reduce_kernel<<<(NT + 3) / 4, 256, 0, stream>>>(
        h_word, offsets, ssrc, sw, SEG_WT, NT, S, degf, wsumf);
    reduce_kernel<<<(NT + 3) / 4, 256, 0, stream>>>(
        Wh_tt, offsets, ssrc, sw, SEG_TT, NT, S, degf, nullptr);
    reduce_kernel<<<(NDOC + 3) / 4, 256, 0, stream>>>(
        h_word, offsets, ssrc, sw, SEG_WD, NDOC, S, degf, wsumf);
    reduce_kernel<<<(NDOC + 3) / 4, 256, 0, stream>>>(
        Wh_td, offsets, ssrc, sw, SEG_TD, NDOC, S, degf, nullptr);

    // ---- Final projections + cross-relation sums ----
    mm_kernel<<<(NT + 31) / 32, 256, 0, stream>>>(
        S + (long long)SEG_WT * D, W_wt, degf + SEG_WT, wsumf + SEG_WT, b_wt,
        S + (long long)SEG_TT * D, degf + SEG_TT, h_topic, NT);
    mm_kernel<<<(NDOC + 31) / 32, 256, 0, stream>>>(
        S + (long long)SEG_WD * D, W_wd, degf + SEG_WD, wsumf + SEG_WD, b_wd,
        S + (long long)SEG_TD * D, degf + SEG_TD, h_doc, NDOC);

    (void)n_in; (void)in_sizes; (void)out_size; (void)ws_size;
}

// Round 4
// 486.311 us; speedup vs baseline: 5.8081x; 1.2896x over previous
//
#include <hip/hip_runtime.h>

#define D 128
constexpr int NW = 30000;
constexpr int NT = 2000;
constexpr int NDOC = 20000;
constexpr int NSLOT = NW + NT + NT + NDOC + NDOC;   // 74000 destination slots
constexpr int SEG_WW = 0;
constexpr int SEG_WT = NW;                 // 30000
constexpr int SEG_TT = NW + NT;            // 32000
constexpr int SEG_WD = NW + 2 * NT;        // 34000
constexpr int SEG_TD = NW + 2 * NT + NDOC; // 54000
constexpr int NP2 = NT + NT + NDOC + NDOC; // 44000 phase-2 slots (contiguous from SEG_WT)

struct RelDesc { const int* src; const int* dst; const float* w; int e0; int seg; };
struct Rels { RelDesc r[5]; };

// ---------------------------------------------------------------------------
// CSR build: merged count -> scan -> merged scatter. Only int atomics.
// ---------------------------------------------------------------------------
__global__ __launch_bounds__(256) void count_all_kernel(
    Rels R, int Etot, int* __restrict__ counts)
{
    int e = blockIdx.x * 256 + threadIdx.x;
    if (e >= Etot) return;
    const int* dstp; int base, seg;
    if (e < R.r[1].e0)      { dstp = R.r[0].dst; base = R.r[0].e0; seg = R.r[0].seg; }
    else if (e < R.r[2].e0) { dstp = R.r[1].dst; base = R.r[1].e0; seg = R.r[1].seg; }
    else if (e < R.r[3].e0) { dstp = R.r[2].dst; base = R.r[2].e0; seg = R.r[2].seg; }
    else if (e < R.r[4].e0) { dstp = R.r[3].dst; base = R.r[3].e0; seg = R.r[3].seg; }
    else                    { dstp = R.r[4].dst; base = R.r[4].e0; seg = R.r[4].seg; }
    atomicAdd(&counts[seg + dstp[e - base]], 1);
}

__global__ __launch_bounds__(256) void scatter_all_kernel(
    Rels R, int Etot, int* __restrict__ cursor, int2* __restrict__ edata)
{
    int e = blockIdx.x * 256 + threadIdx.x;
    if (e >= Etot) return;
    const int* srcp; const int* dstp; const float* wp; int base, seg;
    if (e < R.r[1].e0)      { srcp = R.r[0].src; dstp = R.r[0].dst; wp = R.r[0].w; base = R.r[0].e0; seg = R.r[0].seg; }
    else if (e < R.r[2].e0) { srcp = R.r[1].src; dstp = R.r[1].dst; wp = R.r[1].w; base = R.r[1].e0; seg = R.r[1].seg; }
    else if (e < R.r[3].e0) { srcp = R.r[2].src; dstp = R.r[2].dst; wp = R.r[2].w; base = R.r[2].e0; seg = R.r[2].seg; }
    else if (e < R.r[4].e0) { srcp = R.r[3].src; dstp = R.r[3].dst; wp = R.r[3].w; base = R.r[3].e0; seg = R.r[3].seg; }
    else                    { srcp = R.r[4].src; dstp = R.r[4].dst; wp = R.r[4].w; base = R.r[4].e0; seg = R.r[4].seg; }
    int le = e - base;
    int p = atomicAdd(&cursor[seg + dstp[le]], 1);
    edata[p] = make_int2(srcp[le], __float_as_int(wp[le]));
}

// phase 1: per-block exclusive scan of counts into offsets, block totals out.
__global__ __launch_bounds__(256) void scan1_kernel(
    const int* __restrict__ counts, int n, int n1,
    int* __restrict__ offsets, int* __restrict__ blocksums)
{
    __shared__ int tmp[256];
    int tid = threadIdx.x;
    int i = blockIdx.x * 256 + tid;
    int v = (i < n) ? counts[i] : 0;
    tmp[tid] = v;
    __syncthreads();
    for (int off = 1; off < 256; off <<= 1) {
        int t = (tid >= off) ? tmp[tid - off] : 0;
        __syncthreads();
        tmp[tid] += t;
        __syncthreads();
    }
    if (i < n1) offsets[i] = tmp[tid] - v;   // exclusive
    if (tid == 255) blocksums[blockIdx.x] = tmp[255];
}

// phase 2: add carry (sum of preceding block totals), duplicate into cursor.
__global__ __launch_bounds__(256) void scan3_kernel(
    int* __restrict__ offsets, int* __restrict__ cursor,
    const int* __restrict__ blocksums, int n1)
{
    __shared__ int red[256];
    int tid = threadIdx.x;
    int acc = 0;
    for (int i = tid; i < blockIdx.x; i += 256) acc += blocksums[i];
    red[tid] = acc;
    __syncthreads();
    for (int off = 128; off > 0; off >>= 1) {
        if (tid < off) red[tid] += red[tid + off];
        __syncthreads();
    }
    int carry = red[0];
    int i = blockIdx.x * 256 + tid;
    if (i < n1) {
        int v = offsets[i] + carry;
        offsets[i] = v;
        cursor[i] = v;
    }
}

// ---------------------------------------------------------------------------
// Segmented reduction core: one wave per dst slot.
// 32 lanes x float4 cover one 128-float row; halves (lane>>5) take alternate
// edges -> each gather instruction fetches 2 rows, 4-edge unrolled body x
// pragma-unroll 2 = up to 4 gathers in flight. Halves combined via shfl_xor.
// ---------------------------------------------------------------------------
__device__ __forceinline__ void reduce_one(
    const float* __restrict__ X, const int* __restrict__ offsets,
    const int2* __restrict__ edata, int slot, int lane,
    float* __restrict__ S, float* __restrict__ degf, float* __restrict__ wsumf)
{
    int start = offsets[slot], end = offsets[slot + 1];
    int half = lane >> 5;
    int q = (lane & 31) * 4;   // float offset within row
    float4 acc = make_float4(0.f, 0.f, 0.f, 0.f);
    float wacc = 0.f;
    int j = start;
#pragma unroll 2
    for (; j + 4 <= end; j += 4) {
        int2 ea = edata[j + half];
        int2 eb = edata[j + 2 + half];
        float4 va = *(const float4*)(X + (size_t)ea.x * D + q);
        float4 vb = *(const float4*)(X + (size_t)eb.x * D + q);
        float wa = __int_as_float(ea.y);
        float wb = __int_as_float(eb.y);
        acc.x = fmaf(wa, va.x, acc.x); acc.y = fmaf(wa, va.y, acc.y);
        acc.z = fmaf(wa, va.z, acc.z); acc.w = fmaf(wa, va.w, acc.w);
        acc.x = fmaf(wb, vb.x, acc.x); acc.y = fmaf(wb, vb.y, acc.y);
        acc.z = fmaf(wb, vb.z, acc.z); acc.w = fmaf(wb, vb.w, acc.w);
        wacc += wa + wb;
    }
    for (; j < end; j += 2) {               // tail: 1..3 edges, 2 per step
        int jj = j + half;
        int2 e = edata[jj < end ? jj : (end - 1)];
        float w = (jj < end) ? __int_as_float(e.y) : 0.f;
        float4 v = *(const float4*)(X + (size_t)e.x * D + q);
        acc.x = fmaf(w, v.x, acc.x); acc.y = fmaf(w, v.y, acc.y);
        acc.z = fmaf(w, v.z, acc.z); acc.w = fmaf(w, v.w, acc.w);
        wacc += w;
    }
    acc.x += __shfl_xor(acc.x, 32);
    acc.y += __shfl_xor(acc.y, 32);
    acc.z += __shfl_xor(acc.z, 32);
    acc.w += __shfl_xor(acc.w, 32);
    wacc  += __shfl_xor(wacc, 32);
    if (half == 0)
        *(float4*)(S + (size_t)slot * D + q) = acc;
    if (lane == 0) {
        degf[slot] = (float)(end - start);
        if (wsumf) wsumf[slot] = wacc;
    }
}

__global__ __launch_bounds__(256) void reduce_kernel(
    const float* __restrict__ X, const int* __restrict__ offsets,
    const int2* __restrict__ edata, int slot0, int nslots,
    float* __restrict__ S, float* __restrict__ degf, float* __restrict__ wsumf)
{
    int rel = blockIdx.x * 4 + (threadIdx.x >> 6);
    if (rel >= nslots) return;
    reduce_one(X, offsets, edata, slot0 + rel, threadIdx.x & 63, S, degf, wsumf);
}

// Merged phase-2 reduce: slots SEG_WT..NSLOT (wt,tt,wd,td contiguous).
__global__ __launch_bounds__(256) void reduce_p2_kernel(
    const float* __restrict__ h_word, const float* __restrict__ Wh_tt,
    const float* __restrict__ Wh_td, const int* __restrict__ offsets,
    const int2* __restrict__ edata, float* __restrict__ S,
    float* __restrict__ degf, float* __restrict__ wsumf)
{
    int rel = blockIdx.x * 4 + (threadIdx.x >> 6);
    if (rel >= NP2) return;
    const float* X;
    if (rel < NT)                X = h_word;  // wt
    else if (rel < 2 * NT)       X = Wh_tt;   // tt
    else if (rel < 2 * NT + NDOC) X = h_word; // wd
    else                         X = Wh_td;   // td
    reduce_one(X, offsets, edata, SEG_WT + rel, threadIdx.x & 63, S, degf, wsumf);
}

// ---------------------------------------------------------------------------
// Y = X @ W  [n x 128] x [128 x 128], optionally normalized (see round 1).
// ---------------------------------------------------------------------------
__global__ __launch_bounds__(256) void mm_kernel(
    const float* __restrict__ X, const float* __restrict__ W,
    const float* __restrict__ deg, const float* __restrict__ wsum,
    const float* __restrict__ bias,
    const float* __restrict__ T, const float* __restrict__ degT,
    float* __restrict__ Y, int n)
{
    __shared__ float Wl[D * D];
    __shared__ float xs[32][D];
    int tid = threadIdx.x;

    for (int i = tid; i < D * D / 4; i += 256)
        ((float4*)Wl)[i] = ((const float4*)W)[i];

    int row0 = blockIdx.x * 32;
    for (int i = tid; i < 32 * (D / 4); i += 256) {
        int r = i / (D / 4);
        int c4 = i % (D / 4);
        float4 v = make_float4(0.f, 0.f, 0.f, 0.f);
        if (row0 + r < n)
            v = ((const float4*)(X + (long long)(row0 + r) * D))[c4];
        ((float4*)&xs[r][0])[c4] = v;
    }
    __syncthreads();

    int cg = tid & 31;
    int rg = tid >> 5;
    int col0 = cg * 4;

    float acc[4][4];
#pragma unroll
    for (int j = 0; j < 4; ++j)
#pragma unroll
        for (int c = 0; c < 4; ++c) acc[j][c] = 0.f;

#pragma unroll 4
    for (int k = 0; k < D; ++k) {
        float4 wv = *(const float4*)&Wl[k * D + col0];
#pragma unroll
        for (int j = 0; j < 4; ++j) {
            float xv = xs[rg + j * 8][k];
            acc[j][0] = fmaf(xv, wv.x, acc[j][0]);
            acc[j][1] = fmaf(xv, wv.y, acc[j][1]);
            acc[j][2] = fmaf(xv, wv.z, acc[j][2]);
            acc[j][3] = fmaf(xv, wv.w, acc[j][3]);
        }
    }

#pragma unroll
    for (int j = 0; j < 4; ++j) {
        int row = row0 + rg + j * 8;
        if (row >= n) continue;
        float4 y;
        float* yp = &y.x;
        if (deg) {
            float dg = deg[row];
            float ws = wsum ? wsum[row] : 0.f;
#pragma unroll
            for (int c = 0; c < 4; ++c)
                yp[c] = dg > 0.f ? (acc[j][c] + ws * bias[col0 + c]) / dg : 0.f;
            if (T) {
                float dt = degT[row];
                if (dt > 0.f) {
                    float4 tv = *(const float4*)&T[(long long)row * D + col0];
                    y.x += tv.x / dt;
                    y.y += tv.y / dt;
                    y.z += tv.z / dt;
                    y.w += tv.w / dt;
                }
            }
        } else {
#pragma unroll
            for (int c = 0; c < 4; ++c) yp[c] = acc[j][c];
        }
        *(float4*)&Y[(long long)row * D + col0] = y;
    }
}

// 4 simultaneous [NT x 128] @ [128 x 128] products (blockIdx.y selects W/P).
struct MM4 { const float* W[4]; float* P[4]; };
__global__ __launch_bounds__(256) void mm4_kernel(const float* __restrict__ X, MM4 p, int n)
{
    __shared__ float Wl[D * D];
    __shared__ float xs[32][D];
    const float* Wg = p.W[blockIdx.y];
    float* Y = p.P[blockIdx.y];
    int tid = threadIdx.x;

    for (int i = tid; i < D * D / 4; i += 256)
        ((float4*)Wl)[i] = ((const float4*)Wg)[i];

    int row0 = blockIdx.x * 32;
    for (int i = tid; i < 32 * (D / 4); i += 256) {
        int r = i / (D / 4);
        int c4 = i % (D / 4);
        float4 v = make_float4(0.f, 0.f, 0.f, 0.f);
        if (row0 + r < n)
            v = ((const float4*)(X + (long long)(row0 + r) * D))[c4];
        ((float4*)&xs[r][0])[c4] = v;
    }
    __syncthreads();

    int cg = tid & 31;
    int rg = tid >> 5;
    int col0 = cg * 4;

    float acc[4][4];
#pragma unroll
    for (int j = 0; j < 4; ++j)
#pragma unroll
        for (int c = 0; c < 4; ++c) acc[j][c] = 0.f;

#pragma unroll 4
    for (int k = 0; k < D; ++k) {
        float4 wv = *(const float4*)&Wl[k * D + col0];
#pragma unroll
        for (int j = 0; j < 4; ++j) {
            float xv = xs[rg + j * 8][k];
            acc[j][0] = fmaf(xv, wv.x, acc[j][0]);
            acc[j][1] = fmaf(xv, wv.y, acc[j][1]);
            acc[j][2] = fmaf(xv, wv.z, acc[j][2]);
            acc[j][3] = fmaf(xv, wv.w, acc[j][3]);
        }
    }

#pragma unroll
    for (int j = 0; j < 4; ++j) {
        int row = row0 + rg + j * 8;
        if (row >= n) continue;
        *(float4*)&Y[(long long)row * D + col0] =
            make_float4(acc[j][0], acc[j][1], acc[j][2], acc[j][3]);
    }
}

// ---------------------------------------------------------------------------
// Wh_td = P_td + b_td + causal*Pc - rm_td*Pn ; same for tt.
// ---------------------------------------------------------------------------
__global__ __launch_bounds__(256) void combine_topic_kernel(
    const float* __restrict__ P_td, const float* __restrict__ P_tt,
    const float* __restrict__ Pc, const float* __restrict__ Pn,
    const float* __restrict__ effect, const float* __restrict__ bern_td,
    const float* __restrict__ bern_tt,
    const float* __restrict__ b_td, const float* __restrict__ b_tt,
    float* __restrict__ Wh_td, float* __restrict__ Wh_tt)
{
    int i = blockIdx.x * 256 + threadIdx.x;
    if (i >= NT * D) return;
    int row = i >> 7;
    int col = i & (D - 1);
    float eff = effect[row];
    float causal = (eff != 0.f) ? 1.f : 0.f;
    float zero = (eff == 0.f) ? 1.f : 0.f;
    float rmtd = bern_td[row] * zero;
    float rmtt = bern_tt[row] * zero;
    float pc = Pc[i];
    float pn = Pn[i];
    Wh_td[i] = P_td[i] + b_td[col] + causal * pc - rmtd * pn;
    Wh_tt[i] = P_tt[i] + b_tt[col] + causal * pc - rmtt * pn;
}

extern "C" void kernel_launch(void* const* d_in, const int* in_sizes, int n_in,
                              void* d_out, int out_size, void* d_ws, size_t ws_size,
                              hipStream_t stream)
{
    const float* feat_word  = (const float*)d_in[0];
    const float* feat_topic = (const float*)d_in[1];
    const float* effect     = (const float*)d_in[2];
    const float* bern_td    = (const float*)d_in[3];
    const float* bern_tt    = (const float*)d_in[4];
    const int*   src_ww = (const int*)d_in[5];
    const int*   dst_ww = (const int*)d_in[6];
    const float* w_ww   = (const float*)d_in[7];
    const int*   src_wt = (const int*)d_in[8];
    const int*   dst_wt = (const int*)d_in[9];
    const float* w_wt   = (const float*)d_in[10];
    const int*   src_wd = (const int*)d_in[11];
    const int*   dst_wd = (const int*)d_in[12];
    const float* w_wd   = (const float*)d_in[13];
    const int*   src_td = (const int*)d_in[14];
    const int*   dst_td = (const int*)d_in[15];
    const float* w_td   = (const float*)d_in[16];
    const int*   src_tt = (const int*)d_in[17];
    const int*   dst_tt = (const int*)d_in[18];
    const float* w_tt   = (const float*)d_in[19];
    const float* W_ww = (const float*)d_in[20];
    const float* b_ww = (const float*)d_in[21];
    const float* W_wt = (const float*)d_in[22];
    const float* b_wt = (const float*)d_in[23];
    const float* W_wd = (const float*)d_in[24];
    const float* b_wd = (const float*)d_in[25];
    const float* W_td = (const float*)d_in[26];
    const float* b_td = (const float*)d_in[27];
    const float* W_tt = (const float*)d_in[28];
    const float* b_tt = (const float*)d_in[29];
    const float* W_causal = (const float*)d_in[30];
    const float* W_noise  = (const float*)d_in[31];

    const int E_ww = in_sizes[5];
    const int E_wt = in_sizes[8];
    const int E_wd = in_sizes[11];
    const int E_td = in_sizes[14];
    const int E_tt = in_sizes[17];
    const int E_total = E_ww + E_wt + E_wd + E_td + E_tt;

    // ---- workspace layout (4-byte units; edata 8B-aligned) ----
    float* ws = (float*)d_ws;
    float* S      = ws; ws += (long long)NSLOT * D;
    float* degf   = ws; ws += NSLOT;
    float* wsumf  = ws; ws += NSLOT;
    int*   counts   = (int*)ws; ws += NSLOT;
    int*   offsets  = (int*)ws; ws += NSLOT + 1;
    int*   cursor   = (int*)ws; ws += NSLOT + 1;
    int*   blocksums= (int*)ws; ws += 512;
    ws += ((size_t)(ws - (float*)d_ws) & 1);          // pad to 8B alignment
    int2*  edata    = (int2*)ws; ws += (long long)2 * E_total;
    float* Wh_td    = ws;        ws += (long long)NT * D;
    float* Wh_tt    = ws;        ws += (long long)NT * D;
    // P_* buffers overlay the doc-segment region of S (written only by the
    // phase-2 reduce, which launches after combine consumes P_*).
    float* Pbase = S + (long long)SEG_WD * D;
    float* P_td = Pbase;
    float* P_tt = Pbase + (long long)NT * D;
    float* Pc   = Pbase + (long long)2 * NT * D;
    float* Pn   = Pbase + (long long)3 * NT * D;

    hipMemsetAsync(counts, 0, NSLOT * sizeof(int), stream);

    float* h_word  = (float*)d_out;
    float* h_topic = h_word + (long long)NW * D;
    float* h_doc   = h_topic + (long long)NT * D;

    auto nb = [](long long n) { return (unsigned)((n + 255) / 256); };

    Rels R;
    R.r[0] = { src_ww, dst_ww, w_ww, 0, SEG_WW };
    R.r[1] = { src_wt, dst_wt, w_wt, E_ww, SEG_WT };
    R.r[2] = { src_tt, dst_tt, w_tt, E_ww + E_wt, SEG_TT };
    R.r[3] = { src_wd, dst_wd, w_wd, E_ww + E_wt + E_tt, SEG_WD };
    R.r[4] = { src_td, dst_td, w_td, E_ww + E_wt + E_tt + E_wd, SEG_TD };

    // ---- CSR build (merged) ----
    count_all_kernel<<<nb(E_total), 256, 0, stream>>>(R, E_total, counts);
    int n1 = NSLOT + 1;
    scan1_kernel<<<nb(n1), 256, 0, stream>>>(counts, NSLOT, n1, offsets, blocksums);
    scan3_kernel<<<nb(n1), 256, 0, stream>>>(offsets, cursor, blocksums, n1);
    scatter_all_kernel<<<nb(E_total), 256, 0, stream>>>(R, E_total, cursor, edata);

    // ---- Topic-side Wh precompute (independent of reduces) ----
    MM4 m4;
    m4.W[0] = W_td; m4.W[1] = W_tt; m4.W[2] = W_causal; m4.W[3] = W_noise;
    m4.P[0] = P_td; m4.P[1] = P_tt; m4.P[2] = Pc;       m4.P[3] = Pn;
    mm4_kernel<<<dim3((NT + 31) / 32, 4), 256, 0, stream>>>(feat_topic, m4, NT);
    combine_topic_kernel<<<nb(NT * D), 256, 0, stream>>>(
        P_td, P_tt, Pc, Pn, effect, bern_td, bern_tt, b_td, b_tt, Wh_td, Wh_tt);

    // ---- Phase 1: ww reduce + word projection ----
    reduce_kernel<<<(NW + 3) / 4, 256, 0, stream>>>(
        feat_word, offsets, edata, SEG_WW, NW, S, degf, wsumf);
    mm_kernel<<<(NW + 31) / 32, 256, 0, stream>>>(
        S + (long long)SEG_WW * D, W_ww, degf + SEG_WW, wsumf + SEG_WW, b_ww,
        nullptr, nullptr, h_word, NW);

    // ---- Phase 2: merged reduce over wt/tt/wd/td ----
    reduce_p2_kernel<<<(NP2 + 3) / 4, 256, 0, stream>>>(
        h_word, Wh_tt, Wh_td, offsets, edata, S, degf, wsumf);

    // ---- Final projections + cross-relation sums ----
    mm_kernel<<<(NT + 31) / 32, 256, 0, stream>>>(
        S + (long long)SEG_WT * D, W_wt, degf + SEG_WT, wsumf + SEG_WT, b_wt,
        S + (long long)SEG_TT * D, degf + SEG_TT, h_topic, NT);
    mm_kernel<<<(NDOC + 31) / 32, 256, 0, stream>>>(
        S + (long long)SEG_WD * D, W_wd, degf + SEG_WD, wsumf + SEG_WD, b_wd,
        S + (long long)SEG_TD * D, degf + SEG_TD, h_doc, NDOC);

    (void)n_in; (void)in_sizes; (void)out_size; (void)ws_size;
}

// Round 5
// 412.179 us; speedup vs baseline: 6.8527x; 1.1799x over previous
//
#include <hip/hip_runtime.h>

#define D 128
constexpr int NW = 30000;
constexpr int NT = 2000;
constexpr int NDOC = 20000;
constexpr int NSLOT = NW + NT + NT + NDOC + NDOC;   // 74000 destination slots
constexpr int SEG_WW = 0;
constexpr int SEG_WT = NW;                 // 30000
constexpr int SEG_TT = NW + NT;            // 32000
constexpr int SEG_WD = NW + 2 * NT;        // 34000
constexpr int SEG_TD = NW + 2 * NT + NDOC; // 54000
constexpr int NP2 = NT + NT + NDOC + NDOC; // 44000 phase-2 slots

constexpr int BWS = 128;                    // slots per bucket (pow2: slot>>7)
constexpr int NBKT = (NSLOT + BWS - 1) / BWS;  // 579
constexpr int EPB = 8192;                   // edges per partition block

struct RelDesc { const int* src; const int* dst; const float* w; int e0; int seg; };
struct Rels { RelDesc r[5]; };

__device__ __forceinline__ void resolve_rel(const Rels& R, int e,
    const int*& srcp, const int*& dstp, const float*& wp, int& le, int& seg)
{
    int k;
    if (e < R.r[1].e0) k = 0;
    else if (e < R.r[2].e0) k = 1;
    else if (e < R.r[3].e0) k = 2;
    else if (e < R.r[4].e0) k = 3;
    else k = 4;
    srcp = R.r[k].src; dstp = R.r[k].dst; wp = R.r[k].w;
    le = e - R.r[k].e0; seg = R.r[k].seg;
}

// ---------------------------------------------------------------------------
// A1: per-block LDS bucket histogram -> global bucket counts.
// ---------------------------------------------------------------------------
__global__ __launch_bounds__(256) void bucket_count_kernel(
    Rels R, int Etot, int* __restrict__ bucket_count)
{
    __shared__ int hist[NBKT];
    int tid = threadIdx.x;
    for (int i = tid; i < NBKT; i += 256) hist[i] = 0;
    __syncthreads();
    int base_e = blockIdx.x * EPB;
    for (int r = 0; r < EPB / 256; ++r) {
        int e = base_e + r * 256 + tid;
        if (e < Etot) {
            const int *srcp, *dstp; const float* wp; int le, seg;
            resolve_rel(R, e, srcp, dstp, wp, le, seg);
            int g = seg + dstp[le];
            atomicAdd(&hist[g >> 7], 1);
        }
    }
    __syncthreads();
    for (int i = tid; i < NBKT; i += 256)
        if (hist[i]) atomicAdd(&bucket_count[i], hist[i]);
}

// ---------------------------------------------------------------------------
// A2: single-block exclusive scan of bucket counts -> bucket_base/cursor.
// ---------------------------------------------------------------------------
__global__ __launch_bounds__(256) void bucket_scan_kernel(
    const int* __restrict__ bucket_count, int Etot,
    int* __restrict__ bucket_base, int* __restrict__ bucket_cursor,
    int* __restrict__ offsets)
{
    __shared__ int chs[256];
    __shared__ int vals[256 * 3];
    int tid = threadIdx.x;
    int s = 0;
    for (int j = 0; j < 3; ++j) {
        int i = tid * 3 + j;
        int c = (i < NBKT) ? bucket_count[i] : 0;
        vals[tid * 3 + j] = c;
        s += c;
    }
    chs[tid] = s;
    __syncthreads();
    for (int off = 1; off < 256; off <<= 1) {
        int t = (tid >= off) ? chs[tid - off] : 0;
        __syncthreads();
        chs[tid] += t;
        __syncthreads();
    }
    int run = (tid == 0) ? 0 : chs[tid - 1];
    for (int j = 0; j < 3; ++j) {
        int i = tid * 3 + j;
        if (i < NBKT) {
            bucket_base[i] = run;
            bucket_cursor[i] = run;
            run += vals[tid * 3 + j];
        }
    }
    if (tid == 0) { bucket_base[NBKT] = Etot; offsets[NSLOT] = Etot; }
}

// ---------------------------------------------------------------------------
// A3: partition edges into bucket regions. Per-block chunk claiming: one
// global atomic per (block,bucket); writes are ~14-edge contiguous chunks.
// Entry: x = src | (dloc<<15), y = w bits.
// ---------------------------------------------------------------------------
__global__ __launch_bounds__(256) void partition_kernel(
    Rels R, int Etot, int* __restrict__ bucket_cursor, int2* __restrict__ edataA)
{
    __shared__ int hist[NBKT];
    __shared__ int baseL[NBKT];
    __shared__ unsigned short bkt[EPB];
    __shared__ unsigned char dl[EPB];
    int tid = threadIdx.x;
    for (int i = tid; i < NBKT; i += 256) hist[i] = 0;
    __syncthreads();
    int base_e = blockIdx.x * EPB;
    for (int r = 0; r < EPB / 256; ++r) {
        int idx = r * 256 + tid;
        int e = base_e + idx;
        if (e < Etot) {
            const int *srcp, *dstp; const float* wp; int le, seg;
            resolve_rel(R, e, srcp, dstp, wp, le, seg);
            int g = seg + dstp[le];
            bkt[idx] = (unsigned short)(g >> 7);
            dl[idx] = (unsigned char)(g & 127);
            atomicAdd(&hist[g >> 7], 1);
        } else {
            bkt[idx] = 0xFFFF;
        }
    }
    __syncthreads();
    for (int i = tid; i < NBKT; i += 256)
        baseL[i] = hist[i] ? atomicAdd(&bucket_cursor[i], hist[i]) : 0;
    __syncthreads();
    for (int i = tid; i < NBKT; i += 256) hist[i] = 0;
    __syncthreads();
    for (int r = 0; r < EPB / 256; ++r) {
        int idx = r * 256 + tid;
        int e = base_e + idx;
        if (e < Etot) {
            const int *srcp, *dstp; const float* wp; int le, seg;
            resolve_rel(R, e, srcp, dstp, wp, le, seg);
            int b = bkt[idx];
            int rk = atomicAdd(&hist[b], 1);
            edataA[baseL[b] + rk] =
                make_int2(srcp[le] | ((int)dl[idx] << 15), __float_as_int(wp[le]));
        }
    }
}

// ---------------------------------------------------------------------------
// B: one block per bucket. LDS histogram over 128 slots -> scan -> emit
// offsets + place edges in final CSR order (writes stay in one L2 tile).
// ---------------------------------------------------------------------------
__global__ __launch_bounds__(256) void bucket_csr_kernel(
    const int* __restrict__ bucket_base, const int2* __restrict__ edataA,
    int2* __restrict__ edataB, int* __restrict__ offsets)
{
    int k = blockIdx.x;
    int bstart = bucket_base[k], bend = bucket_base[k + 1];
    __shared__ int h2[BWS];
    __shared__ int exc[BWS];
    int tid = threadIdx.x;
    if (tid < BWS) h2[tid] = 0;
    __syncthreads();
    for (int i = bstart + tid; i < bend; i += 256) {
        int dloc = (edataA[i].x >> 15) & 127;
        atomicAdd(&h2[dloc], 1);
    }
    __syncthreads();
    if (tid < BWS) exc[tid] = h2[tid];
    __syncthreads();
    for (int off = 1; off < BWS; off <<= 1) {
        int t = 0;
        if (tid < BWS && tid >= off) t = exc[tid - off];
        __syncthreads();
        if (tid < BWS) exc[tid] += t;
        __syncthreads();
    }
    if (tid < BWS) exc[tid] -= h2[tid];   // exclusive
    __syncthreads();
    int slot0 = k * BWS;
    if (tid < BWS && slot0 + tid < NSLOT) offsets[slot0 + tid] = bstart + exc[tid];
    if (tid < BWS) h2[tid] = 0;
    __syncthreads();
    for (int i = bstart + tid; i < bend; i += 256) {
        int2 e = edataA[i];
        int dloc = (e.x >> 15) & 127;
        int rk = atomicAdd(&h2[dloc], 1);
        edataB[bstart + exc[dloc] + rk] = e;
    }
}

// ---------------------------------------------------------------------------
// Segmented reduction core (one wave per dst slot; src = e.x & 0x7FFF).
// ---------------------------------------------------------------------------
__device__ __forceinline__ void reduce_one(
    const float* __restrict__ X, const int* __restrict__ offsets,
    const int2* __restrict__ edata, int slot, int lane,
    float* __restrict__ S, float* __restrict__ degf, float* __restrict__ wsumf)
{
    int start = offsets[slot], end = offsets[slot + 1];
    int half = lane >> 5;
    int q = (lane & 31) * 4;
    float4 acc = make_float4(0.f, 0.f, 0.f, 0.f);
    float wacc = 0.f;
    int j = start;
#pragma unroll 2
    for (; j + 4 <= end; j += 4) {
        int2 ea = edata[j + half];
        int2 eb = edata[j + 2 + half];
        float4 va = *(const float4*)(X + (size_t)(ea.x & 0x7FFF) * D + q);
        float4 vb = *(const float4*)(X + (size_t)(eb.x & 0x7FFF) * D + q);
        float wa = __int_as_float(ea.y);
        float wb = __int_as_float(eb.y);
        acc.x = fmaf(wa, va.x, acc.x); acc.y = fmaf(wa, va.y, acc.y);
        acc.z = fmaf(wa, va.z, acc.z); acc.w = fmaf(wa, va.w, acc.w);
        acc.x = fmaf(wb, vb.x, acc.x); acc.y = fmaf(wb, vb.y, acc.y);
        acc.z = fmaf(wb, vb.z, acc.z); acc.w = fmaf(wb, vb.w, acc.w);
        wacc += wa + wb;
    }
    for (; j < end; j += 2) {
        int jj = j + half;
        int2 e = edata[jj < end ? jj : (end - 1)];
        float w = (jj < end) ? __int_as_float(e.y) : 0.f;
        float4 v = *(const float4*)(X + (size_t)(e.x & 0x7FFF) * D + q);
        acc.x = fmaf(w, v.x, acc.x); acc.y = fmaf(w, v.y, acc.y);
        acc.z = fmaf(w, v.z, acc.z); acc.w = fmaf(w, v.w, acc.w);
        wacc += w;
    }
    acc.x += __shfl_xor(acc.x, 32);
    acc.y += __shfl_xor(acc.y, 32);
    acc.z += __shfl_xor(acc.z, 32);
    acc.w += __shfl_xor(acc.w, 32);
    wacc  += __shfl_xor(wacc, 32);
    if (half == 0)
        *(float4*)(S + (size_t)slot * D + q) = acc;
    if (lane == 0) {
        degf[slot] = (float)(end - start);
        if (wsumf) wsumf[slot] = wacc;
    }
}

__global__ __launch_bounds__(256) void reduce_kernel(
    const float* __restrict__ X, const int* __restrict__ offsets,
    const int2* __restrict__ edata, int slot0, int nslots,
    float* __restrict__ S, float* __restrict__ degf, float* __restrict__ wsumf)
{
    int rel = blockIdx.x * 4 + (threadIdx.x >> 6);
    if (rel >= nslots) return;
    reduce_one(X, offsets, edata, slot0 + rel, threadIdx.x & 63, S, degf, wsumf);
}

__global__ __launch_bounds__(256) void reduce_p2_kernel(
    const float* __restrict__ h_word, const float* __restrict__ Wh_tt,
    const float* __restrict__ Wh_td, const int* __restrict__ offsets,
    const int2* __restrict__ edata, float* __restrict__ S,
    float* __restrict__ degf, float* __restrict__ wsumf)
{
    int rel = blockIdx.x * 4 + (threadIdx.x >> 6);
    if (rel >= NP2) return;
    const float* X;
    if (rel < NT)                 X = h_word;  // wt
    else if (rel < 2 * NT)        X = Wh_tt;   // tt
    else if (rel < 2 * NT + NDOC) X = h_word;  // wd
    else                          X = Wh_td;   // td
    reduce_one(X, offsets, edata, SEG_WT + rel, threadIdx.x & 63, S, degf, wsumf);
}

// ---------------------------------------------------------------------------
// Y = X @ W  [n x 128] x [128 x 128], optionally normalized (see round 1).
// ---------------------------------------------------------------------------
__global__ __launch_bounds__(256) void mm_kernel(
    const float* __restrict__ X, const float* __restrict__ W,
    const float* __restrict__ deg, const float* __restrict__ wsum,
    const float* __restrict__ bias,
    const float* __restrict__ T, const float* __restrict__ degT,
    float* __restrict__ Y, int n)
{
    __shared__ float Wl[D * D];
    __shared__ float xs[32][D];
    int tid = threadIdx.x;

    for (int i = tid; i < D * D / 4; i += 256)
        ((float4*)Wl)[i] = ((const float4*)W)[i];

    int row0 = blockIdx.x * 32;
    for (int i = tid; i < 32 * (D / 4); i += 256) {
        int r = i / (D / 4);
        int c4 = i % (D / 4);
        float4 v = make_float4(0.f, 0.f, 0.f, 0.f);
        if (row0 + r < n)
            v = ((const float4*)(X + (long long)(row0 + r) * D))[c4];
        ((float4*)&xs[r][0])[c4] = v;
    }
    __syncthreads();

    int cg = tid & 31;
    int rg = tid >> 5;
    int col0 = cg * 4;

    float acc[4][4];
#pragma unroll
    for (int j = 0; j < 4; ++j)
#pragma unroll
        for (int c = 0; c < 4; ++c) acc[j][c] = 0.f;

#pragma unroll 4
    for (int k = 0; k < D; ++k) {
        float4 wv = *(const float4*)&Wl[k * D + col0];
#pragma unroll
        for (int j = 0; j < 4; ++j) {
            float xv = xs[rg + j * 8][k];
            acc[j][0] = fmaf(xv, wv.x, acc[j][0]);
            acc[j][1] = fmaf(xv, wv.y, acc[j][1]);
            acc[j][2] = fmaf(xv, wv.z, acc[j][2]);
            acc[j][3] = fmaf(xv, wv.w, acc[j][3]);
        }
    }

#pragma unroll
    for (int j = 0; j < 4; ++j) {
        int row = row0 + rg + j * 8;
        if (row >= n) continue;
        float4 y;
        float* yp = &y.x;
        if (deg) {
            float dg = deg[row];
            float ws = wsum ? wsum[row] : 0.f;
#pragma unroll
            for (int c = 0; c < 4; ++c)
                yp[c] = dg > 0.f ? (acc[j][c] + ws * bias[col0 + c]) / dg : 0.f;
            if (T) {
                float dt = degT[row];
                if (dt > 0.f) {
                    float4 tv = *(const float4*)&T[(long long)row * D + col0];
                    y.x += tv.x / dt;
                    y.y += tv.y / dt;
                    y.z += tv.z / dt;
                    y.w += tv.w / dt;
                }
            }
        } else {
#pragma unroll
            for (int c = 0; c < 4; ++c) yp[c] = acc[j][c];
        }
        *(float4*)&Y[(long long)row * D + col0] = y;
    }
}

// 4 simultaneous [NT x 128] @ [128 x 128] products (blockIdx.y selects W/P).
struct MM4 { const float* W[4]; float* P[4]; };
__global__ __launch_bounds__(256) void mm4_kernel(const float* __restrict__ X, MM4 p, int n)
{
    __shared__ float Wl[D * D];
    __shared__ float xs[32][D];
    const float* Wg = p.W[blockIdx.y];
    float* Y = p.P[blockIdx.y];
    int tid = threadIdx.x;

    for (int i = tid; i < D * D / 4; i += 256)
        ((float4*)Wl)[i] = ((const float4*)Wg)[i];

    int row0 = blockIdx.x * 32;
    for (int i = tid; i < 32 * (D / 4); i += 256) {
        int r = i / (D / 4);
        int c4 = i % (D / 4);
        float4 v = make_float4(0.f, 0.f, 0.f, 0.f);
        if (row0 + r < n)
            v = ((const float4*)(X + (long long)(row0 + r) * D))[c4];
        ((float4*)&xs[r][0])[c4] = v;
    }
    __syncthreads();

    int cg = tid & 31;
    int rg = tid >> 5;
    int col0 = cg * 4;

    float acc[4][4];
#pragma unroll
    for (int j = 0; j < 4; ++j)
#pragma unroll
        for (int c = 0; c < 4; ++c) acc[j][c] = 0.f;

#pragma unroll 4
    for (int k = 0; k < D; ++k) {
        float4 wv = *(const float4*)&Wl[k * D + col0];
#pragma unroll
        for (int j = 0; j < 4; ++j) {
            float xv = xs[rg + j * 8][k];
            acc[j][0] = fmaf(xv, wv.x, acc[j][0]);
            acc[j][1] = fmaf(xv, wv.y, acc[j][1]);
            acc[j][2] = fmaf(xv, wv.z, acc[j][2]);
            acc[j][3] = fmaf(xv, wv.w, acc[j][3]);
        }
    }

#pragma unroll
    for (int j = 0; j < 4; ++j) {
        int row = row0 + rg + j * 8;
        if (row >= n) continue;
        *(float4*)&Y[(long long)row * D + col0] =
            make_float4(acc[j][0], acc[j][1], acc[j][2], acc[j][3]);
    }
}

// ---------------------------------------------------------------------------
// Wh_td = P_td + b_td + causal*Pc - rm_td*Pn ; same for tt.
// ---------------------------------------------------------------------------
__global__ __launch_bounds__(256) void combine_topic_kernel(
    const float* __restrict__ P_td, const float* __restrict__ P_tt,
    const float* __restrict__ Pc, const float* __restrict__ Pn,
    const float* __restrict__ effect, const float* __restrict__ bern_td,
    const float* __restrict__ bern_tt,
    const float* __restrict__ b_td, const float* __restrict__ b_tt,
    float* __restrict__ Wh_td, float* __restrict__ Wh_tt)
{
    int i = blockIdx.x * 256 + threadIdx.x;
    if (i >= NT * D) return;
    int row = i >> 7;
    int col = i & (D - 1);
    float eff = effect[row];
    float causal = (eff != 0.f) ? 1.f : 0.f;
    float zero = (eff == 0.f) ? 1.f : 0.f;
    float rmtd = bern_td[row] * zero;
    float rmtt = bern_tt[row] * zero;
    float pc = Pc[i];
    float pn = Pn[i];
    Wh_td[i] = P_td[i] + b_td[col] + causal * pc - rmtd * pn;
    Wh_tt[i] = P_tt[i] + b_tt[col] + causal * pc - rmtt * pn;
}

extern "C" void kernel_launch(void* const* d_in, const int* in_sizes, int n_in,
                              void* d_out, int out_size, void* d_ws, size_t ws_size,
                              hipStream_t stream)
{
    const float* feat_word  = (const float*)d_in[0];
    const float* feat_topic = (const float*)d_in[1];
    const float* effect     = (const float*)d_in[2];
    const float* bern_td    = (const float*)d_in[3];
    const float* bern_tt    = (const float*)d_in[4];
    const int*   src_ww = (const int*)d_in[5];
    const int*   dst_ww = (const int*)d_in[6];
    const float* w_ww   = (const float*)d_in[7];
    const int*   src_wt = (const int*)d_in[8];
    const int*   dst_wt = (const int*)d_in[9];
    const float* w_wt   = (const float*)d_in[10];
    const int*   src_wd = (const int*)d_in[11];
    const int*   dst_wd = (const int*)d_in[12];
    const float* w_wd   = (const float*)d_in[13];
    const int*   src_td = (const int*)d_in[14];
    const int*   dst_td = (const int*)d_in[15];
    const float* w_td   = (const float*)d_in[16];
    const int*   src_tt = (const int*)d_in[17];
    const int*   dst_tt = (const int*)d_in[18];
    const float* w_tt   = (const float*)d_in[19];
    const float* W_ww = (const float*)d_in[20];
    const float* b_ww = (const float*)d_in[21];
    const float* W_wt = (const float*)d_in[22];
    const float* b_wt = (const float*)d_in[23];
    const float* W_wd = (const float*)d_in[24];
    const float* b_wd = (const float*)d_in[25];
    const float* W_td = (const float*)d_in[26];
    const float* b_td = (const float*)d_in[27];
    const float* W_tt = (const float*)d_in[28];
    const float* b_tt = (const float*)d_in[29];
    const float* W_causal = (const float*)d_in[30];
    const float* W_noise  = (const float*)d_in[31];

    const int E_ww = in_sizes[5];
    const int E_wt = in_sizes[8];
    const int E_wd = in_sizes[11];
    const int E_td = in_sizes[14];
    const int E_tt = in_sizes[17];
    const int E_total = E_ww + E_wt + E_wd + E_td + E_tt;

    // ---- workspace layout (4-byte units; int2 buffers 8B-aligned) ----
    float* ws = (float*)d_ws;
    float* S      = ws; ws += (long long)NSLOT * D;
    float* degf   = ws; ws += NSLOT;
    float* wsumf  = ws; ws += NSLOT;
    int*   offsets      = (int*)ws; ws += NSLOT + 1;
    int*   bucket_count = (int*)ws; ws += NBKT;
    int*   bucket_base  = (int*)ws; ws += NBKT + 1;
    int*   bucket_cursor= (int*)ws; ws += NBKT;
    ws += ((size_t)(ws - (float*)d_ws) & 1);          // 8B align
    int2*  edataB   = (int2*)ws; ws += (long long)2 * E_total;
    float* Wh_td    = ws;        ws += (long long)NT * D;
    float* Wh_tt    = ws;        ws += (long long)NT * D;
    // Overlays inside S's doc-segment region (SEG_WD.. = 5.12M floats):
    //   P_* : first 4*NT*D floats (written by mm4, consumed by combine)
    //   edataA : next 2*E_total ints (written by A3, dead after pass B)
    // Both are dead before the phase-2 reduce writes these S slots.
    float* Pbase = S + (long long)SEG_WD * D;
    float* P_td = Pbase;
    float* P_tt = Pbase + (long long)NT * D;
    float* Pc   = Pbase + (long long)2 * NT * D;
    float* Pn   = Pbase + (long long)3 * NT * D;
    int2*  edataA = (int2*)(Pbase + (long long)4 * NT * D);

    hipMemsetAsync(bucket_count, 0, NBKT * sizeof(int), stream);

    float* h_word  = (float*)d_out;
    float* h_topic = h_word + (long long)NW * D;
    float* h_doc   = h_topic + (long long)NT * D;

    auto nb = [](long long n) { return (unsigned)((n + 255) / 256); };

    Rels R;
    R.r[0] = { src_ww, dst_ww, w_ww, 0, SEG_WW };
    R.r[1] = { src_wt, dst_wt, w_wt, E_ww, SEG_WT };
    R.r[2] = { src_tt, dst_tt, w_tt, E_ww + E_wt, SEG_TT };
    R.r[3] = { src_wd, dst_wd, w_wd, E_ww + E_wt + E_tt, SEG_WD };
    R.r[4] = { src_td, dst_td, w_td, E_ww + E_wt + E_tt + E_wd, SEG_TD };

    // ---- Topic-side Wh precompute (independent; P_* region untouched below
    //      until the phase-2 reduce) ----
    MM4 m4;
    m4.W[0] = W_td; m4.W[1] = W_tt; m4.W[2] = W_causal; m4.W[3] = W_noise;
    m4.P[0] = P_td; m4.P[1] = P_tt; m4.P[2] = Pc;       m4.P[3] = Pn;
    mm4_kernel<<<dim3((NT + 31) / 32, 4), 256, 0, stream>>>(feat_topic, m4, NT);
    combine_topic_kernel<<<nb(NT * D), 256, 0, stream>>>(
        P_td, P_tt, Pc, Pn, effect, bern_td, bern_tt, b_td, b_tt, Wh_td, Wh_tt);

    // ---- CSR build: bucket count -> scan -> partition -> per-bucket CSR ----
    unsigned npb = (unsigned)((E_total + EPB - 1) / EPB);
    bucket_count_kernel<<<npb, 256, 0, stream>>>(R, E_total, bucket_count);
    bucket_scan_kernel<<<1, 256, 0, stream>>>(bucket_count, E_total,
                                              bucket_base, bucket_cursor, offsets);
    partition_kernel<<<npb, 256, 0, stream>>>(R, E_total, bucket_cursor, edataA);
    bucket_csr_kernel<<<NBKT, 256, 0, stream>>>(bucket_base, edataA, edataB, offsets);

    // ---- Phase 1: ww reduce + word projection ----
    reduce_kernel<<<(NW + 3) / 4, 256, 0, stream>>>(
        feat_word, offsets, edataB, SEG_WW, NW, S, degf, wsumf);
    mm_kernel<<<(NW + 31) / 32, 256, 0, stream>>>(
        S + (long long)SEG_WW * D, W_ww, degf + SEG_WW, wsumf + SEG_WW, b_ww,
        nullptr, nullptr, h_word, NW);

    // ---- Phase 2: merged reduce over wt/tt/wd/td ----
    reduce_p2_kernel<<<(NP2 + 3) / 4, 256, 0, stream>>>(
        h_word, Wh_tt, Wh_td, offsets, edataB, S, degf, wsumf);

    // ---- Final projections + cross-relation sums ----
    mm_kernel<<<(NT + 31) / 32, 256, 0, stream>>>(
        S + (long long)SEG_WT * D, W_wt, degf + SEG_WT, wsumf + SEG_WT, b_wt,
        S + (long long)SEG_TT * D, degf + SEG_TT, h_topic, NT);
    mm_kernel<<<(NDOC + 31) / 32, 256, 0, stream>>>(
        S + (long long)SEG_WD * D, W_wd, degf + SEG_WD, wsumf + SEG_WD, b_wd,
        S + (long long)SEG_TD * D, degf + SEG_TD, h_doc, NDOC);

    (void)n_in; (void)in_sizes; (void)out_size; (void)ws_size;
}

// Round 6
// 375.386 us; speedup vs baseline: 7.5243x; 1.0980x over previous
//
#include <hip/hip_runtime.h>

#define D 128
typedef unsigned short u16;
constexpr int NW = 30000;
constexpr int NT = 2000;
constexpr int NDOC = 20000;
constexpr int NSLOT = NW + NT + NT + NDOC + NDOC;   // 74000 destination slots
constexpr int SEG_WW = 0;
constexpr int SEG_WT = NW;                 // 30000
constexpr int SEG_TT = NW + NT;            // 32000
constexpr int SEG_WD = NW + 2 * NT;        // 34000
constexpr int SEG_TD = NW + 2 * NT + NDOC; // 54000
constexpr int NP2 = NT + NT + NDOC + NDOC; // 44000 phase-2 slots

constexpr int BWS = 128;                    // slots per bucket (pow2: slot>>7)
constexpr int NBKT = (NSLOT + BWS - 1) / BWS;  // 579
constexpr int EPB = 2048;                   // edges per partition block (grid ~704)

struct RelDesc { const int* src; const int* dst; const float* w; int e0; int seg; };
struct Rels { RelDesc r[5]; };

__device__ __forceinline__ void resolve_rel(const Rels& R, int e,
    const int*& srcp, const int*& dstp, const float*& wp, int& le, int& seg)
{
    int k;
    if (e < R.r[1].e0) k = 0;
    else if (e < R.r[2].e0) k = 1;
    else if (e < R.r[3].e0) k = 2;
    else if (e < R.r[4].e0) k = 3;
    else k = 4;
    srcp = R.r[k].src; dstp = R.r[k].dst; wp = R.r[k].w;
    le = e - R.r[k].e0; seg = R.r[k].seg;
}

__device__ __forceinline__ float b2f(u16 h)
{
    return __uint_as_float(((unsigned)h) << 16);
}
__device__ __forceinline__ u16 f2b(float f)   // round-to-nearest-even
{
    unsigned u = __float_as_uint(f);
    return (u16)((u + 0x7FFF + ((u >> 16) & 1)) >> 16);
}

// ---------------------------------------------------------------------------
// fp32 -> bf16 table conversion (feat_word): 4 elements per thread.
// ---------------------------------------------------------------------------
__global__ __launch_bounds__(256) void f2b_kernel(
    const float* __restrict__ X, u16* __restrict__ Y, int n4)
{
    int i = blockIdx.x * 256 + threadIdx.x;
    if (i >= n4) return;
    float4 v = ((const float4*)X)[i];
    ushort4 o;
    o.x = f2b(v.x); o.y = f2b(v.y); o.z = f2b(v.z); o.w = f2b(v.w);
    ((ushort4*)Y)[i] = o;
}

// ---------------------------------------------------------------------------
// A1: per-block LDS bucket histogram -> global bucket counts.
// ---------------------------------------------------------------------------
__global__ __launch_bounds__(256) void bucket_count_kernel(
    Rels R, int Etot, int* __restrict__ bucket_count)
{
    __shared__ int hist[NBKT];
    int tid = threadIdx.x;
    for (int i = tid; i < NBKT; i += 256) hist[i] = 0;
    __syncthreads();
    int base_e = blockIdx.x * EPB;
    for (int r = 0; r < EPB / 256; ++r) {
        int e = base_e + r * 256 + tid;
        if (e < Etot) {
            const int *srcp, *dstp; const float* wp; int le, seg;
            resolve_rel(R, e, srcp, dstp, wp, le, seg);
            int g = seg + dstp[le];
            atomicAdd(&hist[g >> 7], 1);
        }
    }
    __syncthreads();
    for (int i = tid; i < NBKT; i += 256)
        if (hist[i]) atomicAdd(&bucket_count[i], hist[i]);
}

// ---------------------------------------------------------------------------
// A2: single-block exclusive scan of bucket counts -> bucket_base/cursor.
// ---------------------------------------------------------------------------
__global__ __launch_bounds__(256) void bucket_scan_kernel(
    const int* __restrict__ bucket_count, int Etot,
    int* __restrict__ bucket_base, int* __restrict__ bucket_cursor,
    int* __restrict__ offsets)
{
    __shared__ int chs[256];
    __shared__ int vals[256 * 3];
    int tid = threadIdx.x;
    int s = 0;
    for (int j = 0; j < 3; ++j) {
        int i = tid * 3 + j;
        int c = (i < NBKT) ? bucket_count[i] : 0;
        vals[tid * 3 + j] = c;
        s += c;
    }
    chs[tid] = s;
    __syncthreads();
    for (int off = 1; off < 256; off <<= 1) {
        int t = (tid >= off) ? chs[tid - off] : 0;
        __syncthreads();
        chs[tid] += t;
        __syncthreads();
    }
    int run = (tid == 0) ? 0 : chs[tid - 1];
    for (int j = 0; j < 3; ++j) {
        int i = tid * 3 + j;
        if (i < NBKT) {
            bucket_base[i] = run;
            bucket_cursor[i] = run;
            run += vals[tid * 3 + j];
        }
    }
    if (tid == 0) { bucket_base[NBKT] = Etot; offsets[NSLOT] = Etot; }
}

// ---------------------------------------------------------------------------
// A3: partition edges into bucket regions. One global atomic per
// (block,bucket); writes are contiguous chunks. x = src | (dloc<<15).
// ---------------------------------------------------------------------------
__global__ __launch_bounds__(256) void partition_kernel(
    Rels R, int Etot, int* __restrict__ bucket_cursor, int2* __restrict__ edataA)
{
    __shared__ int hist[NBKT];
    __shared__ int baseL[NBKT];
    __shared__ u16 bkt[EPB];
    __shared__ unsigned char dl[EPB];
    int tid = threadIdx.x;
    for (int i = tid; i < NBKT; i += 256) hist[i] = 0;
    __syncthreads();
    int base_e = blockIdx.x * EPB;
    for (int r = 0; r < EPB / 256; ++r) {
        int idx = r * 256 + tid;
        int e = base_e + idx;
        if (e < Etot) {
            const int *srcp, *dstp; const float* wp; int le, seg;
            resolve_rel(R, e, srcp, dstp, wp, le, seg);
            int g = seg + dstp[le];
            bkt[idx] = (u16)(g >> 7);
            dl[idx] = (unsigned char)(g & 127);
            atomicAdd(&hist[g >> 7], 1);
        } else {
            bkt[idx] = 0xFFFF;
        }
    }
    __syncthreads();
    for (int i = tid; i < NBKT; i += 256)
        baseL[i] = hist[i] ? atomicAdd(&bucket_cursor[i], hist[i]) : 0;
    __syncthreads();
    for (int i = tid; i < NBKT; i += 256) hist[i] = 0;
    __syncthreads();
    for (int r = 0; r < EPB / 256; ++r) {
        int idx = r * 256 + tid;
        int e = base_e + idx;
        if (e < Etot) {
            const int *srcp, *dstp; const float* wp; int le, seg;
            resolve_rel(R, e, srcp, dstp, wp, le, seg);
            int b = bkt[idx];
            int rk = atomicAdd(&hist[b], 1);
            edataA[baseL[b] + rk] =
                make_int2(srcp[le] | ((int)dl[idx] << 15), __float_as_int(wp[le]));
        }
    }
}

// ---------------------------------------------------------------------------
// B: one block per bucket. LDS histogram over 128 slots -> scan -> emit
// offsets + place edges in final CSR order (writes stay in one L2 tile).
// ---------------------------------------------------------------------------
__global__ __launch_bounds__(256) void bucket_csr_kernel(
    const int* __restrict__ bucket_base, const int2* __restrict__ edataA,
    int2* __restrict__ edataB, int* __restrict__ offsets)
{
    int k = blockIdx.x;
    int bstart = bucket_base[k], bend = bucket_base[k + 1];
    __shared__ int h2[BWS];
    __shared__ int exc[BWS];
    int tid = threadIdx.x;
    if (tid < BWS) h2[tid] = 0;
    __syncthreads();
    for (int i = bstart + tid; i < bend; i += 256) {
        int dloc = (edataA[i].x >> 15) & 127;
        atomicAdd(&h2[dloc], 1);
    }
    __syncthreads();
    if (tid < BWS) exc[tid] = h2[tid];
    __syncthreads();
    for (int off = 1; off < BWS; off <<= 1) {
        int t = 0;
        if (tid < BWS && tid >= off) t = exc[tid - off];
        __syncthreads();
        if (tid < BWS) exc[tid] += t;
        __syncthreads();
    }
    if (tid < BWS) exc[tid] -= h2[tid];   // exclusive
    __syncthreads();
    int slot0 = k * BWS;
    if (tid < BWS && slot0 + tid < NSLOT) offsets[slot0 + tid] = bstart + exc[tid];
    if (tid < BWS) h2[tid] = 0;
    __syncthreads();
    for (int i = bstart + tid; i < bend; i += 256) {
        int2 e = edataA[i];
        int dloc = (e.x >> 15) & 127;
        int rk = atomicAdd(&h2[dloc], 1);
        edataB[bstart + exc[dloc] + rk] = e;
    }
}

// ---------------------------------------------------------------------------
// Segmented reduction core (one wave per dst slot). Gather table is bf16
// (halves fetch bytes); accumulation fp32. src = e.x & 0x7FFF.
// ---------------------------------------------------------------------------
__device__ __forceinline__ void reduce_one(
    const u16* __restrict__ Xb, const int* __restrict__ offsets,
    const int2* __restrict__ edata, int slot, int lane,
    float* __restrict__ S, float* __restrict__ degf, float* __restrict__ wsumf)
{
    int start = offsets[slot], end = offsets[slot + 1];
    int half = lane >> 5;
    int q = (lane & 31) * 4;   // element offset within row (4 per lane)
    float4 acc = make_float4(0.f, 0.f, 0.f, 0.f);
    float wacc = 0.f;
    int j = start;
#pragma unroll 2
    for (; j + 4 <= end; j += 4) {
        int2 ea = edata[j + half];
        int2 eb = edata[j + 2 + half];
        ushort4 va = *(const ushort4*)(Xb + (size_t)(ea.x & 0x7FFF) * D + q);
        ushort4 vb = *(const ushort4*)(Xb + (size_t)(eb.x & 0x7FFF) * D + q);
        float wa = __int_as_float(ea.y);
        float wb = __int_as_float(eb.y);
        acc.x = fmaf(wa, b2f(va.x), acc.x); acc.y = fmaf(wa, b2f(va.y), acc.y);
        acc.z = fmaf(wa, b2f(va.z), acc.z); acc.w = fmaf(wa, b2f(va.w), acc.w);
        acc.x = fmaf(wb, b2f(vb.x), acc.x); acc.y = fmaf(wb, b2f(vb.y), acc.y);
        acc.z = fmaf(wb, b2f(vb.z), acc.z); acc.w = fmaf(wb, b2f(vb.w), acc.w);
        wacc += wa + wb;
    }
    for (; j < end; j += 2) {
        int jj = j + half;
        int2 e = edata[jj < end ? jj : (end - 1)];
        float w = (jj < end) ? __int_as_float(e.y) : 0.f;
        ushort4 v = *(const ushort4*)(Xb + (size_t)(e.x & 0x7FFF) * D + q);
        acc.x = fmaf(w, b2f(v.x), acc.x); acc.y = fmaf(w, b2f(v.y), acc.y);
        acc.z = fmaf(w, b2f(v.z), acc.z); acc.w = fmaf(w, b2f(v.w), acc.w);
        wacc += w;
    }
    acc.x += __shfl_xor(acc.x, 32);
    acc.y += __shfl_xor(acc.y, 32);
    acc.z += __shfl_xor(acc.z, 32);
    acc.w += __shfl_xor(acc.w, 32);
    wacc  += __shfl_xor(wacc, 32);
    if (half == 0)
        *(float4*)(S + (size_t)slot * D + q) = acc;
    if (lane == 0) {
        degf[slot] = (float)(end - start);
        if (wsumf) wsumf[slot] = wacc;
    }
}

__global__ __launch_bounds__(256) void reduce_kernel(
    const u16* __restrict__ Xb, const int* __restrict__ offsets,
    const int2* __restrict__ edata, int slot0, int nslots,
    float* __restrict__ S, float* __restrict__ degf, float* __restrict__ wsumf)
{
    int rel = blockIdx.x * 4 + (threadIdx.x >> 6);
    if (rel >= nslots) return;
    reduce_one(Xb, offsets, edata, slot0 + rel, threadIdx.x & 63, S, degf, wsumf);
}

__global__ __launch_bounds__(256) void reduce_p2_kernel(
    const u16* __restrict__ hw16, const u16* __restrict__ wtt16,
    const u16* __restrict__ wtd16, const int* __restrict__ offsets,
    const int2* __restrict__ edata, float* __restrict__ S,
    float* __restrict__ degf, float* __restrict__ wsumf)
{
    int rel = blockIdx.x * 4 + (threadIdx.x >> 6);
    if (rel >= NP2) return;
    const u16* X;
    if (rel < NT)                 X = hw16;   // wt
    else if (rel < 2 * NT)        X = wtt16;  // tt
    else if (rel < 2 * NT + NDOC) X = hw16;   // wd
    else                          X = wtd16;  // td
    reduce_one(X, offsets, edata, SEG_WT + rel, threadIdx.x & 63, S, degf, wsumf);
}

// ---------------------------------------------------------------------------
// Y = X @ W  [n x 128] x [128 x 128], optionally normalized; optional bf16
// mirror output Yb (for gather tables).
// ---------------------------------------------------------------------------
__global__ __launch_bounds__(256) void mm_kernel(
    const float* __restrict__ X, const float* __restrict__ W,
    const float* __restrict__ deg, const float* __restrict__ wsum,
    const float* __restrict__ bias,
    const float* __restrict__ T, const float* __restrict__ degT,
    float* __restrict__ Y, u16* __restrict__ Yb, int n)
{
    __shared__ float Wl[D * D];
    __shared__ float xs[32][D];
    int tid = threadIdx.x;

    for (int i = tid; i < D * D / 4; i += 256)
        ((float4*)Wl)[i] = ((const float4*)W)[i];

    int row0 = blockIdx.x * 32;
    for (int i = tid; i < 32 * (D / 4); i += 256) {
        int r = i / (D / 4);
        int c4 = i % (D / 4);
        float4 v = make_float4(0.f, 0.f, 0.f, 0.f);
        if (row0 + r < n)
            v = ((const float4*)(X + (long long)(row0 + r) * D))[c4];
        ((float4*)&xs[r][0])[c4] = v;
    }
    __syncthreads();

    int cg = tid & 31;
    int rg = tid >> 5;
    int col0 = cg * 4;

    float acc[4][4];
#pragma unroll
    for (int j = 0; j < 4; ++j)
#pragma unroll
        for (int c = 0; c < 4; ++c) acc[j][c] = 0.f;

#pragma unroll 4
    for (int k = 0; k < D; ++k) {
        float4 wv = *(const float4*)&Wl[k * D + col0];
#pragma unroll
        for (int j = 0; j < 4; ++j) {
            float xv = xs[rg + j * 8][k];
            acc[j][0] = fmaf(xv, wv.x, acc[j][0]);
            acc[j][1] = fmaf(xv, wv.y, acc[j][1]);
            acc[j][2] = fmaf(xv, wv.z, acc[j][2]);
            acc[j][3] = fmaf(xv, wv.w, acc[j][3]);
        }
    }

#pragma unroll
    for (int j = 0; j < 4; ++j) {
        int row = row0 + rg + j * 8;
        if (row >= n) continue;
        float4 y;
        float* yp = &y.x;
        if (deg) {
            float dg = deg[row];
            float ws = wsum ? wsum[row] : 0.f;
#pragma unroll
            for (int c = 0; c < 4; ++c)
                yp[c] = dg > 0.f ? (acc[j][c] + ws * bias[col0 + c]) / dg : 0.f;
            if (T) {
                float dt = degT[row];
                if (dt > 0.f) {
                    float4 tv = *(const float4*)&T[(long long)row * D + col0];
                    y.x += tv.x / dt;
                    y.y += tv.y / dt;
                    y.z += tv.z / dt;
                    y.w += tv.w / dt;
                }
            }
        } else {
#pragma unroll
            for (int c = 0; c < 4; ++c) yp[c] = acc[j][c];
        }
        *(float4*)&Y[(long long)row * D + col0] = y;
        if (Yb) {
            ushort4 o;
            o.x = f2b(y.x); o.y = f2b(y.y); o.z = f2b(y.z); o.w = f2b(y.w);
            *(ushort4*)&Yb[(long long)row * D + col0] = o;
        }
    }
}

// 4 simultaneous [NT x 128] @ [128 x 128] products (blockIdx.y selects W/P).
struct MM4 { const float* W[4]; float* P[4]; };
__global__ __launch_bounds__(256) void mm4_kernel(const float* __restrict__ X, MM4 p, int n)
{
    __shared__ float Wl[D * D];
    __shared__ float xs[32][D];
    const float* Wg = p.W[blockIdx.y];
    float* Y = p.P[blockIdx.y];
    int tid = threadIdx.x;

    for (int i = tid; i < D * D / 4; i += 256)
        ((float4*)Wl)[i] = ((const float4*)Wg)[i];

    int row0 = blockIdx.x * 32;
    for (int i = tid; i < 32 * (D / 4); i += 256) {
        int r = i / (D / 4);
        int c4 = i % (D / 4);
        float4 v = make_float4(0.f, 0.f, 0.f, 0.f);
        if (row0 + r < n)
            v = ((const float4*)(X + (long long)(row0 + r) * D))[c4];
        ((float4*)&xs[r][0])[c4] = v;
    }
    __syncthreads();

    int cg = tid & 31;
    int rg = tid >> 5;
    int col0 = cg * 4;

    float acc[4][4];
#pragma unroll
    for (int j = 0; j < 4; ++j)
#pragma unroll
        for (int c = 0; c < 4; ++c) acc[j][c] = 0.f;

#pragma unroll 4
    for (int k = 0; k < D; ++k) {
        float4 wv = *(const float4*)&Wl[k * D + col0];
#pragma unroll
        for (int j = 0; j < 4; ++j) {
            float xv = xs[rg + j * 8][k];
            acc[j][0] = fmaf(xv, wv.x, acc[j][0]);
            acc[j][1] = fmaf(xv, wv.y, acc[j][1]);
            acc[j][2] = fmaf(xv, wv.z, acc[j][2]);
            acc[j][3] = fmaf(xv, wv.w, acc[j][3]);
        }
    }

#pragma unroll
    for (int j = 0; j < 4; ++j) {
        int row = row0 + rg + j * 8;
        if (row >= n) continue;
        *(float4*)&Y[(long long)row * D + col0] =
            make_float4(acc[j][0], acc[j][1], acc[j][2], acc[j][3]);
    }
}

// ---------------------------------------------------------------------------
// Wh_td = P_td + b_td + causal*Pc - rm_td*Pn ; same for tt. Emits bf16
// (only consumed by gathers).
// ---------------------------------------------------------------------------
__global__ __launch_bounds__(256) void combine_topic_kernel(
    const float* __restrict__ P_td, const float* __restrict__ P_tt,
    const float* __restrict__ Pc, const float* __restrict__ Pn,
    const float* __restrict__ effect, const float* __restrict__ bern_td,
    const float* __restrict__ bern_tt,
    const float* __restrict__ b_td, const float* __restrict__ b_tt,
    u16* __restrict__ wtd16, u16* __restrict__ wtt16)
{
    int i = blockIdx.x * 256 + threadIdx.x;
    if (i >= NT * D) return;
    int row = i >> 7;
    int col = i & (D - 1);
    float eff = effect[row];
    float causal = (eff != 0.f) ? 1.f : 0.f;
    float zero = (eff == 0.f) ? 1.f : 0.f;
    float rmtd = bern_td[row] * zero;
    float rmtt = bern_tt[row] * zero;
    float pc = Pc[i];
    float pn = Pn[i];
    wtd16[i] = f2b(P_td[i] + b_td[col] + causal * pc - rmtd * pn);
    wtt16[i] = f2b(P_tt[i] + b_tt[col] + causal * pc - rmtt * pn);
}

extern "C" void kernel_launch(void* const* d_in, const int* in_sizes, int n_in,
                              void* d_out, int out_size, void* d_ws, size_t ws_size,
                              hipStream_t stream)
{
    const float* feat_word  = (const float*)d_in[0];
    const float* feat_topic = (const float*)d_in[1];
    const float* effect     = (const float*)d_in[2];
    const float* bern_td    = (const float*)d_in[3];
    const float* bern_tt    = (const float*)d_in[4];
    const int*   src_ww = (const int*)d_in[5];
    const int*   dst_ww = (const int*)d_in[6];
    const float* w_ww   = (const float*)d_in[7];
    const int*   src_wt = (const int*)d_in[8];
    const int*   dst_wt = (const int*)d_in[9];
    const float* w_wt   = (const float*)d_in[10];
    const int*   src_wd = (const int*)d_in[11];
    const int*   dst_wd = (const int*)d_in[12];
    const float* w_wd   = (const float*)d_in[13];
    const int*   src_td = (const int*)d_in[14];
    const int*   dst_td = (const int*)d_in[15];
    const float* w_td   = (const float*)d_in[16];
    const int*   src_tt = (const int*)d_in[17];
    const int*   dst_tt = (const int*)d_in[18];
    const float* w_tt   = (const float*)d_in[19];
    const float* W_ww = (const float*)d_in[20];
    const float* b_ww = (const float*)d_in[21];
    const float* W_wt = (const float*)d_in[22];
    const float* b_wt = (const float*)d_in[23];
    const float* W_wd = (const float*)d_in[24];
    const float* b_wd = (const float*)d_in[25];
    const float* W_td = (const float*)d_in[26];
    const float* b_td = (const float*)d_in[27];
    const float* W_tt = (const float*)d_in[28];
    const float* b_tt = (const float*)d_in[29];
    const float* W_causal = (const float*)d_in[30];
    const float* W_noise  = (const float*)d_in[31];

    const int E_ww = in_sizes[5];
    const int E_wt = in_sizes[8];
    const int E_wd = in_sizes[11];
    const int E_td = in_sizes[14];
    const int E_tt = in_sizes[17];
    const int E_total = E_ww + E_wt + E_wd + E_td + E_tt;

    // ---- workspace layout (4-byte units; int2 buffers 8B-aligned) ----
    float* ws = (float*)d_ws;
    float* S      = ws; ws += (long long)NSLOT * D;
    float* degf   = ws; ws += NSLOT;
    float* wsumf  = ws; ws += NSLOT;
    int*   offsets      = (int*)ws; ws += NSLOT + 1;
    int*   bucket_count = (int*)ws; ws += NBKT;
    int*   bucket_base  = (int*)ws; ws += NBKT + 1;
    int*   bucket_cursor= (int*)ws; ws += NBKT;
    ws += ((size_t)(ws - (float*)d_ws) & 1);          // 8B align
    int2*  edataB   = (int2*)ws; ws += (long long)2 * E_total;
    u16*   fw16     = (u16*)ws;  ws += (long long)NW * D / 2;   // bf16 feat_word
    u16*   hw16     = (u16*)ws;  ws += (long long)NW * D / 2;   // bf16 h_word
    u16*   wtd16    = (u16*)ws;  ws += (long long)NT * D / 2;
    u16*   wtt16    = (u16*)ws;  ws += (long long)NT * D / 2;
    // Overlays inside S's doc-segment region ((NSLOT-SEG_WD)*D = 5.12M floats):
    //   P_* : first 4*NT*D = 1.02M floats (written by mm4, dead after combine)
    //   edataA : next 2*E_total = 2.88M ints (written by A3, dead after pass B)
    // Both dead before the phase-2 reduce writes these S slots.
    float* Pbase = S + (long long)SEG_WD * D;
    float* P_td = Pbase;
    float* P_tt = Pbase + (long long)NT * D;
    float* Pc   = Pbase + (long long)2 * NT * D;
    float* Pn   = Pbase + (long long)3 * NT * D;
    int2*  edataA = (int2*)(Pbase + (long long)4 * NT * D);

    hipMemsetAsync(bucket_count, 0, NBKT * sizeof(int), stream);

    float* h_word  = (float*)d_out;
    float* h_topic = h_word + (long long)NW * D;
    float* h_doc   = h_topic + (long long)NT * D;

    auto nb = [](long long n) { return (unsigned)((n + 255) / 256); };

    Rels R;
    R.r[0] = { src_ww, dst_ww, w_ww, 0, SEG_WW };
    R.r[1] = { src_wt, dst_wt, w_wt, E_ww, SEG_WT };
    R.r[2] = { src_tt, dst_tt, w_tt, E_ww + E_wt, SEG_TT };
    R.r[3] = { src_wd, dst_wd, w_wd, E_ww + E_wt + E_tt, SEG_WD };
    R.r[4] = { src_td, dst_td, w_td, E_ww + E_wt + E_tt + E_wd, SEG_TD };

    // ---- bf16 gather table for feat_word ----
    f2b_kernel<<<nb((long long)NW * D / 4), 256, 0, stream>>>(
        feat_word, fw16, NW * D / 4);

    // ---- Topic-side Wh precompute ----
    MM4 m4;
    m4.W[0] = W_td; m4.W[1] = W_tt; m4.W[2] = W_causal; m4.W[3] = W_noise;
    m4.P[0] = P_td; m4.P[1] = P_tt; m4.P[2] = Pc;       m4.P[3] = Pn;
    mm4_kernel<<<dim3((NT + 31) / 32, 4), 256, 0, stream>>>(feat_topic, m4, NT);
    combine_topic_kernel<<<nb(NT * D), 256, 0, stream>>>(
        P_td, P_tt, Pc, Pn, effect, bern_td, bern_tt, b_td, b_tt, wtd16, wtt16);

    // ---- CSR build: bucket count -> scan -> partition -> per-bucket CSR ----
    unsigned npb = (unsigned)((E_total + EPB - 1) / EPB);
    bucket_count_kernel<<<npb, 256, 0, stream>>>(R, E_total, bucket_count);
    bucket_scan_kernel<<<1, 256, 0, stream>>>(bucket_count, E_total,
                                              bucket_base, bucket_cursor, offsets);
    partition_kernel<<<npb, 256, 0, stream>>>(R, E_total, bucket_cursor, edataA);
    bucket_csr_kernel<<<NBKT, 256, 0, stream>>>(bucket_base, edataA, edataB, offsets);

    // ---- Phase 1: ww reduce + word projection (fp32 out + bf16 mirror) ----
    reduce_kernel<<<(NW + 3) / 4, 256, 0, stream>>>(
        fw16, offsets, edataB, SEG_WW, NW, S, degf, wsumf);
    mm_kernel<<<(NW + 31) / 32, 256, 0, stream>>>(
        S + (long long)SEG_WW * D, W_ww, degf + SEG_WW, wsumf + SEG_WW, b_ww,
        nullptr, nullptr, h_word, hw16, NW);

    // ---- Phase 2: merged reduce over wt/tt/wd/td ----
    reduce_p2_kernel<<<(NP2 + 3) / 4, 256, 0, stream>>>(
        hw16, wtt16, wtd16, offsets, edataB, S, degf, wsumf);

    // ---- Final projections + cross-relation sums ----
    mm_kernel<<<(NT + 31) / 32, 256, 0, stream>>>(
        S + (long long)SEG_WT * D, W_wt, degf + SEG_WT, wsumf + SEG_WT, b_wt,
        S + (long long)SEG_TT * D, degf + SEG_TT, h_topic, nullptr, NT);
    mm_kernel<<<(NDOC + 31) / 32, 256, 0, stream>>>(
        S + (long long)SEG_WD * D, W_wd, degf + SEG_WD, wsumf + SEG_WD, b_wd,
        S + (long long)SEG_TD * D, degf + SEG_TD, h_doc, nullptr, NDOC);

    (void)n_in; (void)in_sizes; (void)out_size; (void)ws_size;
}

// Round 7
// 362.544 us; speedup vs baseline: 7.7909x; 1.0354x over previous
//
#include <hip/hip_runtime.h>

#define D 128
typedef unsigned short u16;
constexpr int NW = 30000;
constexpr int NT = 2000;
constexpr int NDOC = 20000;
constexpr int NSLOT = NW + NT + NT + NDOC + NDOC;   // 74000 destination slots
constexpr int SEG_WW = 0;
constexpr int SEG_WT = NW;                 // 30000
constexpr int SEG_TT = NW + NT;            // 32000
constexpr int SEG_WD = NW + 2 * NT;        // 34000
constexpr int SEG_TD = NW + 2 * NT + NDOC; // 54000
constexpr int NP2 = NT + NT + NDOC + NDOC; // 44000 phase-2 slots

constexpr int BWS = 128;                    // slots per bucket (pow2: slot>>7)
constexpr int NBKT = (NSLOT + BWS - 1) / BWS;  // 579
constexpr int EPB = 2048;                   // edges per partition block (grid ~704)

struct RelDesc { const int* src; const int* dst; const float* w; int e0; int seg; };
struct Rels { RelDesc r[5]; };

__device__ __forceinline__ void resolve_rel(const Rels& R, int e,
    const int*& srcp, const int*& dstp, const float*& wp, int& le, int& seg)
{
    int k;
    if (e < R.r[1].e0) k = 0;
    else if (e < R.r[2].e0) k = 1;
    else if (e < R.r[3].e0) k = 2;
    else if (e < R.r[4].e0) k = 3;
    else k = 4;
    srcp = R.r[k].src; dstp = R.r[k].dst; wp = R.r[k].w;
    le = e - R.r[k].e0; seg = R.r[k].seg;
}

__device__ __forceinline__ float b2f(u16 h)
{
    return __uint_as_float(((unsigned)h) << 16);
}
__device__ __forceinline__ u16 f2b(float f)   // round-to-nearest-even
{
    unsigned u = __float_as_uint(f);
    return (u16)((u + 0x7FFF + ((u >> 16) & 1)) >> 16);
}

// ---------------------------------------------------------------------------
// fp32 -> bf16 table conversion (feat_word): 4 elements per thread.
// ---------------------------------------------------------------------------
__global__ __launch_bounds__(256) void f2b_kernel(
    const float* __restrict__ X, u16* __restrict__ Y, int n4)
{
    int i = blockIdx.x * 256 + threadIdx.x;
    if (i >= n4) return;
    float4 v = ((const float4*)X)[i];
    ushort4 o;
    o.x = f2b(v.x); o.y = f2b(v.y); o.z = f2b(v.z); o.w = f2b(v.w);
    ((ushort4*)Y)[i] = o;
}

// ---------------------------------------------------------------------------
// A1: per-block LDS bucket histogram -> global bucket counts.
// ---------------------------------------------------------------------------
__global__ __launch_bounds__(256) void bucket_count_kernel(
    Rels R, int Etot, int* __restrict__ bucket_count)
{
    __shared__ int hist[NBKT];
    int tid = threadIdx.x;
    for (int i = tid; i < NBKT; i += 256) hist[i] = 0;
    __syncthreads();
    int base_e = blockIdx.x * EPB;
    for (int r = 0; r < EPB / 256; ++r) {
        int e = base_e + r * 256 + tid;
        if (e < Etot) {
            const int *srcp, *dstp; const float* wp; int le, seg;
            resolve_rel(R, e, srcp, dstp, wp, le, seg);
            int g = seg + dstp[le];
            atomicAdd(&hist[g >> 7], 1);
        }
    }
    __syncthreads();
    for (int i = tid; i < NBKT; i += 256)
        if (hist[i]) atomicAdd(&bucket_count[i], hist[i]);
}

// ---------------------------------------------------------------------------
// A2: single-block exclusive scan of bucket counts -> bucket_base/cursor.
// ---------------------------------------------------------------------------
__global__ __launch_bounds__(256) void bucket_scan_kernel(
    const int* __restrict__ bucket_count, int Etot,
    int* __restrict__ bucket_base, int* __restrict__ bucket_cursor,
    int* __restrict__ offsets)
{
    __shared__ int chs[256];
    __shared__ int vals[256 * 3];
    int tid = threadIdx.x;
    int s = 0;
    for (int j = 0; j < 3; ++j) {
        int i = tid * 3 + j;
        int c = (i < NBKT) ? bucket_count[i] : 0;
        vals[tid * 3 + j] = c;
        s += c;
    }
    chs[tid] = s;
    __syncthreads();
    for (int off = 1; off < 256; off <<= 1) {
        int t = (tid >= off) ? chs[tid - off] : 0;
        __syncthreads();
        chs[tid] += t;
        __syncthreads();
    }
    int run = (tid == 0) ? 0 : chs[tid - 1];
    for (int j = 0; j < 3; ++j) {
        int i = tid * 3 + j;
        if (i < NBKT) {
            bucket_base[i] = run;
            bucket_cursor[i] = run;
            run += vals[tid * 3 + j];
        }
    }
    if (tid == 0) { bucket_base[NBKT] = Etot; offsets[NSLOT] = Etot; }
}

// ---------------------------------------------------------------------------
// A3: partition edges into bucket regions. One global atomic per
// (block,bucket); writes are contiguous chunks. x = src | (dloc<<15).
// ---------------------------------------------------------------------------
__global__ __launch_bounds__(256) void partition_kernel(
    Rels R, int Etot, int* __restrict__ bucket_cursor, int2* __restrict__ edataA)
{
    __shared__ int hist[NBKT];
    __shared__ int baseL[NBKT];
    __shared__ u16 bkt[EPB];
    __shared__ unsigned char dl[EPB];
    int tid = threadIdx.x;
    for (int i = tid; i < NBKT; i += 256) hist[i] = 0;
    __syncthreads();
    int base_e = blockIdx.x * EPB;
    for (int r = 0; r < EPB / 256; ++r) {
        int idx = r * 256 + tid;
        int e = base_e + idx;
        if (e < Etot) {
            const int *srcp, *dstp; const float* wp; int le, seg;
            resolve_rel(R, e, srcp, dstp, wp, le, seg);
            int g = seg + dstp[le];
            bkt[idx] = (u16)(g >> 7);
            dl[idx] = (unsigned char)(g & 127);
            atomicAdd(&hist[g >> 7], 1);
        } else {
            bkt[idx] = 0xFFFF;
        }
    }
    __syncthreads();
    for (int i = tid; i < NBKT; i += 256)
        baseL[i] = hist[i] ? atomicAdd(&bucket_cursor[i], hist[i]) : 0;
    __syncthreads();
    for (int i = tid; i < NBKT; i += 256) hist[i] = 0;
    __syncthreads();
    for (int r = 0; r < EPB / 256; ++r) {
        int idx = r * 256 + tid;
        int e = base_e + idx;
        if (e < Etot) {
            const int *srcp, *dstp; const float* wp; int le, seg;
            resolve_rel(R, e, srcp, dstp, wp, le, seg);
            int b = bkt[idx];
            int rk = atomicAdd(&hist[b], 1);
            edataA[baseL[b] + rk] =
                make_int2(srcp[le] | ((int)dl[idx] << 15), __float_as_int(wp[le]));
        }
    }
}

// ---------------------------------------------------------------------------
// B: one block (1024 threads = 16 waves) per bucket. LDS histogram over 128
// slots -> scan -> emit offsets + place edges in final CSR order. 1024
// threads (vs 256) for latency hiding: this kernel was occupancy-starved at
// 4 waves/block (42us, OccupancyPercent 4.4, all pipes idle).
// ---------------------------------------------------------------------------
__global__ __launch_bounds__(1024) void bucket_csr_kernel(
    const int* __restrict__ bucket_base, const int2* __restrict__ edataA,
    int2* __restrict__ edataB, int* __restrict__ offsets)
{
    int k = blockIdx.x;
    int bstart = bucket_base[k], bend = bucket_base[k + 1];
    __shared__ int h2[BWS];
    __shared__ int exc[BWS];
    int tid = threadIdx.x;
    if (tid < BWS) h2[tid] = 0;
    __syncthreads();
    for (int i = bstart + tid; i < bend; i += 1024) {
        int dloc = (edataA[i].x >> 15) & 127;
        atomicAdd(&h2[dloc], 1);
    }
    __syncthreads();
    if (tid < BWS) exc[tid] = h2[tid];
    __syncthreads();
    for (int off = 1; off < BWS; off <<= 1) {
        int t = 0;
        if (tid < BWS && tid >= off) t = exc[tid - off];
        __syncthreads();
        if (tid < BWS) exc[tid] += t;
        __syncthreads();
    }
    if (tid < BWS) exc[tid] -= h2[tid];   // exclusive
    __syncthreads();
    int slot0 = k * BWS;
    if (tid < BWS && slot0 + tid < NSLOT) offsets[slot0 + tid] = bstart + exc[tid];
    if (tid < BWS) h2[tid] = 0;
    __syncthreads();
    for (int i = bstart + tid; i < bend; i += 1024) {
        int2 e = edataA[i];
        int dloc = (e.x >> 15) & 127;
        int rk = atomicAdd(&h2[dloc], 1);
        edataB[bstart + exc[dloc] + rk] = e;
    }
}

// ---------------------------------------------------------------------------
// Segmented reduction core (one wave per dst slot). Gather table is bf16
// (halves fetch bytes); accumulation fp32. src = e.x & 0x7FFF.
// ---------------------------------------------------------------------------
__device__ __forceinline__ void reduce_one(
    const u16* __restrict__ Xb, const int* __restrict__ offsets,
    const int2* __restrict__ edata, int slot, int lane,
    float* __restrict__ S, float* __restrict__ degf, float* __restrict__ wsumf)
{
    int start = offsets[slot], end = offsets[slot + 1];
    int half = lane >> 5;
    int q = (lane & 31) * 4;   // element offset within row (4 per lane)
    float4 acc = make_float4(0.f, 0.f, 0.f, 0.f);
    float wacc = 0.f;
    int j = start;
#pragma unroll 2
    for (; j + 4 <= end; j += 4) {
        int2 ea = edata[j + half];
        int2 eb = edata[j + 2 + half];
        ushort4 va = *(const ushort4*)(Xb + (size_t)(ea.x & 0x7FFF) * D + q);
        ushort4 vb = *(const ushort4*)(Xb + (size_t)(eb.x & 0x7FFF) * D + q);
        float wa = __int_as_float(ea.y);
        float wb = __int_as_float(eb.y);
        acc.x = fmaf(wa, b2f(va.x), acc.x); acc.y = fmaf(wa, b2f(va.y), acc.y);
        acc.z = fmaf(wa, b2f(va.z), acc.z); acc.w = fmaf(wa, b2f(va.w), acc.w);
        acc.x = fmaf(wb, b2f(vb.x), acc.x); acc.y = fmaf(wb, b2f(vb.y), acc.y);
        acc.z = fmaf(wb, b2f(vb.z), acc.z); acc.w = fmaf(wb, b2f(vb.w), acc.w);
        wacc += wa + wb;
    }
    for (; j < end; j += 2) {
        int jj = j + half;
        int2 e = edata[jj < end ? jj : (end - 1)];
        float w = (jj < end) ? __int_as_float(e.y) : 0.f;
        ushort4 v = *(const ushort4*)(Xb + (size_t)(e.x & 0x7FFF) * D + q);
        acc.x = fmaf(w, b2f(v.x), acc.x); acc.y = fmaf(w, b2f(v.y), acc.y);
        acc.z = fmaf(w, b2f(v.z), acc.z); acc.w = fmaf(w, b2f(v.w), acc.w);
        wacc += w;
    }
    acc.x += __shfl_xor(acc.x, 32);
    acc.y += __shfl_xor(acc.y, 32);
    acc.z += __shfl_xor(acc.z, 32);
    acc.w += __shfl_xor(acc.w, 32);
    wacc  += __shfl_xor(wacc, 32);
    if (half == 0)
        *(float4*)(S + (size_t)slot * D + q) = acc;
    if (lane == 0) {
        degf[slot] = (float)(end - start);
        if (wsumf) wsumf[slot] = wacc;
    }
}

__global__ __launch_bounds__(256) void reduce_kernel(
    const u16* __restrict__ Xb, const int* __restrict__ offsets,
    const int2* __restrict__ edata, int slot0, int nslots,
    float* __restrict__ S, float* __restrict__ degf, float* __restrict__ wsumf)
{
    int rel = blockIdx.x * 4 + (threadIdx.x >> 6);
    if (rel >= nslots) return;
    reduce_one(Xb, offsets, edata, slot0 + rel, threadIdx.x & 63, S, degf, wsumf);
}

__global__ __launch_bounds__(256) void reduce_p2_kernel(
    const u16* __restrict__ hw16, const u16* __restrict__ wtt16,
    const u16* __restrict__ wtd16, const int* __restrict__ offsets,
    const int2* __restrict__ edata, float* __restrict__ S,
    float* __restrict__ degf, float* __restrict__ wsumf)
{
    int rel = blockIdx.x * 4 + (threadIdx.x >> 6);
    if (rel >= NP2) return;
    const u16* X;
    if (rel < NT)                 X = hw16;   // wt
    else if (rel < 2 * NT)        X = wtt16;  // tt
    else if (rel < 2 * NT + NDOC) X = hw16;   // wd
    else                          X = wtd16;  // td
    reduce_one(X, offsets, edata, SEG_WT + rel, threadIdx.x & 63, S, degf, wsumf);
}

// ---------------------------------------------------------------------------
// Y = X @ W  [n x 128] x [128 x 128], optionally normalized; optional bf16
// mirror output Yb (for gather tables).
// ---------------------------------------------------------------------------
__global__ __launch_bounds__(256) void mm_kernel(
    const float* __restrict__ X, const float* __restrict__ W,
    const float* __restrict__ deg, const float* __restrict__ wsum,
    const float* __restrict__ bias,
    const float* __restrict__ T, const float* __restrict__ degT,
    float* __restrict__ Y, u16* __restrict__ Yb, int n)
{
    __shared__ float Wl[D * D];
    __shared__ float xs[32][D];
    int tid = threadIdx.x;

    for (int i = tid; i < D * D / 4; i += 256)
        ((float4*)Wl)[i] = ((const float4*)W)[i];

    int row0 = blockIdx.x * 32;
    for (int i = tid; i < 32 * (D / 4); i += 256) {
        int r = i / (D / 4);
        int c4 = i % (D / 4);
        float4 v = make_float4(0.f, 0.f, 0.f, 0.f);
        if (row0 + r < n)
            v = ((const float4*)(X + (long long)(row0 + r) * D))[c4];
        ((float4*)&xs[r][0])[c4] = v;
    }
    __syncthreads();

    int cg = tid & 31;
    int rg = tid >> 5;
    int col0 = cg * 4;

    float acc[4][4];
#pragma unroll
    for (int j = 0; j < 4; ++j)
#pragma unroll
        for (int c = 0; c < 4; ++c) acc[j][c] = 0.f;

#pragma unroll 4
    for (int k = 0; k < D; ++k) {
        float4 wv = *(const float4*)&Wl[k * D + col0];
#pragma unroll
        for (int j = 0; j < 4; ++j) {
            float xv = xs[rg + j * 8][k];
            acc[j][0] = fmaf(xv, wv.x, acc[j][0]);
            acc[j][1] = fmaf(xv, wv.y, acc[j][1]);
            acc[j][2] = fmaf(xv, wv.z, acc[j][2]);
            acc[j][3] = fmaf(xv, wv.w, acc[j][3]);
        }
    }

#pragma unroll
    for (int j = 0; j < 4; ++j) {
        int row = row0 + rg + j * 8;
        if (row >= n) continue;
        float4 y;
        float* yp = &y.x;
        if (deg) {
            float dg = deg[row];
            float ws = wsum ? wsum[row] : 0.f;
#pragma unroll
            for (int c = 0; c < 4; ++c)
                yp[c] = dg > 0.f ? (acc[j][c] + ws * bias[col0 + c]) / dg : 0.f;
            if (T) {
                float dt = degT[row];
                if (dt > 0.f) {
                    float4 tv = *(const float4*)&T[(long long)row * D + col0];
                    y.x += tv.x / dt;
                    y.y += tv.y / dt;
                    y.z += tv.z / dt;
                    y.w += tv.w / dt;
                }
            }
        } else {
#pragma unroll
            for (int c = 0; c < 4; ++c) yp[c] = acc[j][c];
        }
        *(float4*)&Y[(long long)row * D + col0] = y;
        if (Yb) {
            ushort4 o;
            o.x = f2b(y.x); o.y = f2b(y.y); o.z = f2b(y.z); o.w = f2b(y.w);
            *(ushort4*)&Yb[(long long)row * D + col0] = o;
        }
    }
}

// 4 simultaneous [NT x 128] @ [128 x 128] products (blockIdx.y selects W/P).
struct MM4 { const float* W[4]; float* P[4]; };
__global__ __launch_bounds__(256) void mm4_kernel(const float* __restrict__ X, MM4 p, int n)
{
    __shared__ float Wl[D * D];
    __shared__ float xs[32][D];
    const float* Wg = p.W[blockIdx.y];
    float* Y = p.P[blockIdx.y];
    int tid = threadIdx.x;

    for (int i = tid; i < D * D / 4; i += 256)
        ((float4*)Wl)[i] = ((const float4*)Wg)[i];

    int row0 = blockIdx.x * 32;
    for (int i = tid; i < 32 * (D / 4); i += 256) {
        int r = i / (D / 4);
        int c4 = i % (D / 4);
        float4 v = make_float4(0.f, 0.f, 0.f, 0.f);
        if (row0 + r < n)
            v = ((const float4*)(X + (long long)(row0 + r) * D))[c4];
        ((float4*)&xs[r][0])[c4] = v;
    }
    __syncthreads();

    int cg = tid & 31;
    int rg = tid >> 5;
    int col0 = cg * 4;

    float acc[4][4];
#pragma unroll
    for (int j = 0; j < 4; ++j)
#pragma unroll
        for (int c = 0; c < 4; ++c) acc[j][c] = 0.f;

#pragma unroll 4
    for (int k = 0; k < D; ++k) {
        float4 wv = *(const float4*)&Wl[k * D + col0];
#pragma unroll
        for (int j = 0; j < 4; ++j) {
            float xv = xs[rg + j * 8][k];
            acc[j][0] = fmaf(xv, wv.x, acc[j][0]);
            acc[j][1] = fmaf(xv, wv.y, acc[j][1]);
            acc[j][2] = fmaf(xv, wv.z, acc[j][2]);
            acc[j][3] = fmaf(xv, wv.w, acc[j][3]);
        }
    }

#pragma unroll
    for (int j = 0; j < 4; ++j) {
        int row = row0 + rg + j * 8;
        if (row >= n) continue;
        *(float4*)&Y[(long long)row * D + col0] =
            make_float4(acc[j][0], acc[j][1], acc[j][2], acc[j][3]);
    }
}

// ---------------------------------------------------------------------------
// Wh_td = P_td + b_td + causal*Pc - rm_td*Pn ; same for tt. Emits bf16
// (only consumed by gathers).
// ---------------------------------------------------------------------------
__global__ __launch_bounds__(256) void combine_topic_kernel(
    const float* __restrict__ P_td, const float* __restrict__ P_tt,
    const float* __restrict__ Pc, const float* __restrict__ Pn,
    const float* __restrict__ effect, const float* __restrict__ bern_td,
    const float* __restrict__ bern_tt,
    const float* __restrict__ b_td, const float* __restrict__ b_tt,
    u16* __restrict__ wtd16, u16* __restrict__ wtt16)
{
    int i = blockIdx.x * 256 + threadIdx.x;
    if (i >= NT * D) return;
    int row = i >> 7;
    int col = i & (D - 1);
    float eff = effect[row];
    float causal = (eff != 0.f) ? 1.f : 0.f;
    float zero = (eff == 0.f) ? 1.f : 0.f;
    float rmtd = bern_td[row] * zero;
    float rmtt = bern_tt[row] * zero;
    float pc = Pc[i];
    float pn = Pn[i];
    wtd16[i] = f2b(P_td[i] + b_td[col] + causal * pc - rmtd * pn);
    wtt16[i] = f2b(P_tt[i] + b_tt[col] + causal * pc - rmtt * pn);
}

extern "C" void kernel_launch(void* const* d_in, const int* in_sizes, int n_in,
                              void* d_out, int out_size, void* d_ws, size_t ws_size,
                              hipStream_t stream)
{
    const float* feat_word  = (const float*)d_in[0];
    const float* feat_topic = (const float*)d_in[1];
    const float* effect     = (const float*)d_in[2];
    const float* bern_td    = (const float*)d_in[3];
    const float* bern_tt    = (const float*)d_in[4];
    const int*   src_ww = (const int*)d_in[5];
    const int*   dst_ww = (const int*)d_in[6];
    const float* w_ww   = (const float*)d_in[7];
    const int*   src_wt = (const int*)d_in[8];
    const int*   dst_wt = (const int*)d_in[9];
    const float* w_wt   = (const float*)d_in[10];
    const int*   src_wd = (const int*)d_in[11];
    const int*   dst_wd = (const int*)d_in[12];
    const float* w_wd   = (const float*)d_in[13];
    const int*   src_td = (const int*)d_in[14];
    const int*   dst_td = (const int*)d_in[15];
    const float* w_td   = (const float*)d_in[16];
    const int*   src_tt = (const int*)d_in[17];
    const int*   dst_tt = (const int*)d_in[18];
    const float* w_tt   = (const float*)d_in[19];
    const float* W_ww = (const float*)d_in[20];
    const float* b_ww = (const float*)d_in[21];
    const float* W_wt = (const float*)d_in[22];
    const float* b_wt = (const float*)d_in[23];
    const float* W_wd = (const float*)d_in[24];
    const float* b_wd = (const float*)d_in[25];
    const float* W_td = (const float*)d_in[26];
    const float* b_td = (const float*)d_in[27];
    const float* W_tt = (const float*)d_in[28];
    const float* b_tt = (const float*)d_in[29];
    const float* W_causal = (const float*)d_in[30];
    const float* W_noise  = (const float*)d_in[31];

    const int E_ww = in_sizes[5];
    const int E_wt = in_sizes[8];
    const int E_wd = in_sizes[11];
    const int E_td = in_sizes[14];
    const int E_tt = in_sizes[17];
    const int E_total = E_ww + E_wt + E_wd + E_td + E_tt;

    // ---- workspace layout (4-byte units; int2 buffers 8B-aligned) ----
    float* ws = (float*)d_ws;
    float* S      = ws; ws += (long long)NSLOT * D;
    float* degf   = ws; ws += NSLOT;
    float* wsumf  = ws; ws += NSLOT;
    int*   offsets      = (int*)ws; ws += NSLOT + 1;
    int*   bucket_count = (int*)ws; ws += NBKT;
    int*   bucket_base  = (int*)ws; ws += NBKT + 1;
    int*   bucket_cursor= (int*)ws; ws += NBKT;
    ws += ((size_t)(ws - (float*)d_ws) & 1);          // 8B align
    int2*  edataB   = (int2*)ws; ws += (long long)2 * E_total;
    u16*   fw16     = (u16*)ws;  ws += (long long)NW * D / 2;   // bf16 feat_word
    u16*   hw16     = (u16*)ws;  ws += (long long)NW * D / 2;   // bf16 h_word
    u16*   wtd16    = (u16*)ws;  ws += (long long)NT * D / 2;
    u16*   wtt16    = (u16*)ws;  ws += (long long)NT * D / 2;
    // Overlays inside S's doc-segment region ((NSLOT-SEG_WD)*D = 5.12M floats):
    //   P_* : first 4*NT*D = 1.02M floats (written by mm4, dead after combine)
    //   edataA : next 2*E_total = 2.88M ints (written by A3, dead after pass B)
    // Both dead before the phase-2 reduce writes these S slots.
    float* Pbase = S + (long long)SEG_WD * D;
    float* P_td = Pbase;
    float* P_tt = Pbase + (long long)NT * D;
    float* Pc   = Pbase + (long long)2 * NT * D;
    float* Pn   = Pbase + (long long)3 * NT * D;
    int2*  edataA = (int2*)(Pbase + (long long)4 * NT * D);

    hipMemsetAsync(bucket_count, 0, NBKT * sizeof(int), stream);

    float* h_word  = (float*)d_out;
    float* h_topic = h_word + (long long)NW * D;
    float* h_doc   = h_topic + (long long)NT * D;

    auto nb = [](long long n) { return (unsigned)((n + 255) / 256); };

    Rels R;
    R.r[0] = { src_ww, dst_ww, w_ww, 0, SEG_WW };
    R.r[1] = { src_wt, dst_wt, w_wt, E_ww, SEG_WT };
    R.r[2] = { src_tt, dst_tt, w_tt, E_ww + E_wt, SEG_TT };
    R.r[3] = { src_wd, dst_wd, w_wd, E_ww + E_wt + E_tt, SEG_WD };
    R.r[4] = { src_td, dst_td, w_td, E_ww + E_wt + E_tt + E_wd, SEG_TD };

    // ---- bf16 gather table for feat_word ----
    f2b_kernel<<<nb((long long)NW * D / 4), 256, 0, stream>>>(
        feat_word, fw16, NW * D / 4);

    // ---- Topic-side Wh precompute ----
    MM4 m4;
    m4.W[0] = W_td; m4.W[1] = W_tt; m4.W[2] = W_causal; m4.W[3] = W_noise;
    m4.P[0] = P_td; m4.P[1] = P_tt; m4.P[2] = Pc;       m4.P[3] = Pn;
    mm4_kernel<<<dim3((NT + 31) / 32, 4), 256, 0, stream>>>(feat_topic, m4, NT);
    combine_topic_kernel<<<nb(NT * D), 256, 0, stream>>>(
        P_td, P_tt, Pc, Pn, effect, bern_td, bern_tt, b_td, b_tt, wtd16, wtt16);

    // ---- CSR build: bucket count -> scan -> partition -> per-bucket CSR ----
    unsigned npb = (unsigned)((E_total + EPB - 1) / EPB);
    bucket_count_kernel<<<npb, 256, 0, stream>>>(R, E_total, bucket_count);
    bucket_scan_kernel<<<1, 256, 0, stream>>>(bucket_count, E_total,
                                              bucket_base, bucket_cursor, offsets);
    partition_kernel<<<npb, 256, 0, stream>>>(R, E_total, bucket_cursor, edataA);
    bucket_csr_kernel<<<NBKT, 1024, 0, stream>>>(bucket_base, edataA, edataB, offsets);

    // ---- Phase 1: ww reduce + word projection (fp32 out + bf16 mirror) ----
    reduce_kernel<<<(NW + 3) / 4, 256, 0, stream>>>(
        fw16, offsets, edataB, SEG_WW, NW, S, degf, wsumf);
    mm_kernel<<<(NW + 31) / 32, 256, 0, stream>>>(
        S + (long long)SEG_WW * D, W_ww, degf + SEG_WW, wsumf + SEG_WW, b_ww,
        nullptr, nullptr, h_word, hw16, NW);

    // ---- Phase 2: merged reduce over wt/tt/wd/td ----
    reduce_p2_kernel<<<(NP2 + 3) / 4, 256, 0, stream>>>(
        hw16, wtt16, wtd16, offsets, edataB, S, degf, wsumf);

    // ---- Final projections + cross-relation sums ----
    mm_kernel<<<(NT + 31) / 32, 256, 0, stream>>>(
        S + (long long)SEG_WT * D, W_wt, degf + SEG_WT, wsumf + SEG_WT, b_wt,
        S + (long long)SEG_TT * D, degf + SEG_TT, h_topic, nullptr, NT);
    mm_kernel<<<(NDOC + 31) / 32, 256, 0, stream>>>(
        S + (long long)SEG_WD * D, W_wd, degf + SEG_WD, wsumf + SEG_WD, b_wd,
        S + (long long)SEG_TD * D, degf + SEG_TD, h_doc, nullptr, NDOC);

    (void)n_in; (void)in_sizes; (void)out_size; (void)ws_size;
}